// Round 8
// baseline (1284.901 us; speedup 1.0000x reference)
//
#include <hip/hip_runtime.h>

typedef short s16x8 __attribute__((ext_vector_type(8)));
typedef short s16x4 __attribute__((ext_vector_type(4)));
typedef float f32x4 __attribute__((ext_vector_type(4)));
typedef unsigned int u32;
typedef unsigned short u16;

#define NT 512
#define DD 64
#define NTH 512

#define CHUNK 1024

// ---------- recurrent kernel LDS (5 h-chunks per parity) ----------
#define P2STRIDE (5*CHUNK)
#define PH0 0
#define PH1 CHUNK
#define PH2 (2*CHUNK)
#define PH3 (3*CHUNK)
#define PH4 (4*CHUNK)
#define FRTOT2 (2*P2STRIDE)   // 10240 u16 = 20 KB
#define NSTEP2 517            // 512 + 5 pipeline stages

// ---------- fallback (round-3) LDS ----------
#define PSTRIDE (7*CHUNK)
#define XIN0 0
#define H0C (2*CHUNK)
#define H1C (3*CHUNK)
#define H2C (4*CHUNK)
#define H3C (5*CHUNK)
#define H4C (6*CHUNK)
#define FRTOT (2*PSTRIDE)
#define NSTEP_FB 517

#define MFMA16(A,B,C) __builtin_amdgcn_mfma_f32_16x16x32_bf16(A,B,C,0,0,0)

__device__ __forceinline__ float sigf(float x){ return 1.0f/(1.0f+__expf(-x)); }
__device__ __forceinline__ float tanhf2(float x){ return 2.0f/(1.0f+__expf(-2.0f*x)) - 1.0f; }

__device__ __forceinline__ u16 f2bf(float f) {
  u32 u = __builtin_bit_cast(u32, f);
  return (u16)((u + 0x7fffu + ((u >> 16) & 1u)) >> 16);
}
__device__ __forceinline__ float bf2f(u16 h) {
  u32 u = ((u32)h) << 16;
  return __builtin_bit_cast(float, u);
}

// barrier WITHOUT the vmcnt(0) drain: LDS visibility only (global ops drain at use)
__device__ __forceinline__ void soft_barrier() {
  asm volatile("s_waitcnt lgkmcnt(0)" ::: "memory");
  __builtin_amdgcn_s_barrier();
  asm volatile("" ::: "memory");
}

__device__ __forceinline__ u32 cvtpk_bf16(float a, float b) {
  u32 r;
  asm("v_cvt_pk_bf16_f32 %0, %1, %2" : "=v"(r) : "v"(a), "v"(b));
  return r;
}

// A-fragment: lane holds A[row0 + (lane&15)][kbase + (lane>>4)*8 + e], zero-padded.
__device__ __forceinline__ void load_wfrag(const float* __restrict__ W, int row0, int nrow, int din,
                                           int kbase, int lane, s16x8& hi, s16x8& lo)
{
  const int m = lane & 15, kb = lane >> 4;
#pragma unroll
  for (int e = 0; e < 8; ++e) {
    int k = kbase + kb*8 + e;
    float v = (m < nrow && k < din) ? W[(size_t)(row0 + m)*din + k] : 0.0f;
    u16 h = f2bf(v);
    hi[e] = (short)h;
    lo[e] = (short)f2bf(v - bf2f(h));
  }
}

// B-fragment read: lane reads B[k=(lane>>4)*8+e][col=lane&15] (hi at +0, lo at +128)
__device__ __forceinline__ void read_b(const u16* base, int lane, s16x8& hi, s16x8& lo)
{
  const int off = ((lane >> 4) << 8) + ((lane & 15) << 3);
  hi = *(const s16x8*)(base + off);
  lo = *(const s16x8*)(base + off + 128);
}

// gate combine + h write (cvt_pk packing); stores only batch columns bb < NB
template<int NB>
__device__ __forceinline__ void combine_write2(
    f32x4 aR, f32x4 aZ, f32x4 aNi, f32x4 aNh,
    float (&hprev)[4], u16* hdst_base, int jbase, int nrow, int lane)
{
  const int bb = lane & 15, q = lane >> 4;
  float hv[4];
#pragma unroll
  for (int i = 0; i < 4; ++i) {
    float rr = sigf(aR[i]);
    float zz = sigf(aZ[i]);
    float nn = tanhf2(aNi[i] + rr*aNh[i]);
    hv[i] = (1.0f - zz)*nn + zz*hprev[i];
    hprev[i] = hv[i];
  }
  if (bb < NB && q*4 < nrow) {
    const int j = jbase + q*4;
    u16* dst = hdst_base + ((j >> 3) << 8) + bb*8 + (j & 7);
    u32 p01 = cvtpk_bf16(hv[0], hv[1]);
    u32 p23 = cvtpk_bf16(hv[2], hv[3]);
    float h0 = __builtin_bit_cast(float, p01 << 16);
    float h1 = __builtin_bit_cast(float, p01 & 0xffff0000u);
    float h2 = __builtin_bit_cast(float, p23 << 16);
    float h3 = __builtin_bit_cast(float, p23 & 0xffff0000u);
    u32 q01 = cvtpk_bf16(hv[0]-h0, hv[1]-h1);
    u32 q23 = cvtpk_bf16(hv[2]-h2, hv[3]-h3);
    uint2 hp_; hp_.x = p01; hp_.y = p23;
    uint2 lp_; lp_.x = q01; lp_.y = q23;
    *(uint2*)dst = hp_;
    *(uint2*)(dst + 128) = lp_;
  }
}

// =====================================================================
// Phase 1: gi0[b][t][96] = Wih0 @ x_imp(b,t) + bih0 (+bhh0 for r,z rows)
// =====================================================================
__global__ __launch_bounds__(256)
void gi0_gemm(const float* __restrict__ X, const float* __restrict__ M, const float* __restrict__ L,
              const float* __restrict__ wih0, const float* __restrict__ bih0,
              const float* __restrict__ bhh0,
              float* __restrict__ gi)
{
  __shared__ u32 xs[128*65];
  const int tid = threadIdx.x;
  const int wv = tid >> 6, lane = tid & 63;
  const int q = lane >> 4;
  const int b = blockIdx.x >> 2;
  const int t0 = (blockIdx.x & 3) * 128;
  const size_t base = ((size_t)b*NT + t0)*DD;

  for (int i = tid; i < 128*64; i += 256) {
    float x = X[base+i], m = M[base+i], l = L[base+i];
    float v = x*m + l*(1.0f - m);
    u16 h = f2bf(v);
    u16 lo2 = f2bf(v - bf2f(h));
    const int t = i >> 6, d = i & 63;
    xs[t*65 + d] = (u32)h | ((u32)lo2 << 16);
  }

  s16x8 Ah[6][2], Al[6][2];
  f32x4 cb[6];
#pragma unroll
  for (int tile = 0; tile < 6; ++tile) {
#pragma unroll
    for (int c = 0; c < 2; ++c)
      load_wfrag(wih0, tile*16, 16, 64, c*32, lane, Ah[tile][c], Al[tile][c]);
#pragma unroll
    for (int i = 0; i < 4; ++i) {
      int row = tile*16 + q*4 + i;
      float bv = bih0[row];
      if (tile < 4) bv += bhh0[row];
      cb[tile][i] = bv;
    }
  }
  __syncthreads();

#pragma unroll
  for (int g2 = 0; g2 < 2; ++g2) {
    const int tloc = g2*64 + wv*16 + (lane & 15);
    s16x8 Bh[2], Bl[2];
#pragma unroll
    for (int c = 0; c < 2; ++c) {
      const u32* p = &xs[tloc*65 + c*32 + q*8];
#pragma unroll
      for (int e = 0; e < 8; ++e) {
        u32 v = p[e];
        Bh[c][e] = (short)(v & 0xffffu);
        Bl[c][e] = (short)(v >> 16);
      }
    }
    float* gp = gi + ((size_t)b*NT + t0 + tloc)*96 + q*4;
#pragma unroll
    for (int tile = 0; tile < 6; ++tile) {
      f32x4 acc = cb[tile];
#pragma unroll
      for (int c = 0; c < 2; ++c) {
        acc = MFMA16(Ah[tile][c], Bh[c], acc);
        acc = MFMA16(Ah[tile][c], Bl[c], acc);
        acc = MFMA16(Al[tile][c], Bh[c], acc);
      }
      *(f32x4*)(gp + tile*16) = acc;
    }
  }
}

// =====================================================================
// Phase 2: recurrent kernel — R5 structure, BB=4, grid 512 (2 blocks/CU)
// =====================================================================
__device__ __forceinline__ void wave_l0(
    const float* __restrict__ Whh, const float* __restrict__ bhh,
    const float* __restrict__ gi, int jbase,
    u16* FRu, int b0, int lane)
{
  s16x8 Ahh[3], Ahl[3];
#pragma unroll
  for (int g = 0; g < 3; ++g)
    load_wfrag(Whh, g*32 + jbase, 16, 32, 0, lane, Ahh[g], Ahl[g]);
  const int q = lane >> 4;
  f32x4 cNh;
#pragma unroll
  for (int i = 0; i < 4; ++i) cNh[i] = bhh[64 + jbase + q*4 + i];
  float hprev[4] = {0.f,0.f,0.f,0.f};

  const float* gp = gi + (size_t)(b0 + (lane & 3)) * ((size_t)NT*96) + jbase + q*4;
  f32x4 gR0, gZ0, gN0, gR1, gZ1, gN1;
  gR0 = *(const f32x4*)(gp); gZ0 = *(const f32x4*)(gp+32); gN0 = *(const f32x4*)(gp+64); gp += 96;
  gR1 = *(const f32x4*)(gp); gZ1 = *(const f32x4*)(gp+32); gN1 = *(const f32x4*)(gp+64); gp += 96;

  for (int s = 0; s < NSTEP2; ++s) {
    const int par = s & 1, rp = par ^ 1;
    f32x4 gR2 = {}, gZ2 = {}, gN2 = {};
    if (s + 2 < NT) {
      gR2 = *(const f32x4*)(gp); gZ2 = *(const f32x4*)(gp+32); gN2 = *(const f32x4*)(gp+64); gp += 96;
    }
    if (s < NT) {
      f32x4 aR = gR0, aZ = gZ0, aNi = gN0, aNh = cNh;   // biases pre-folded in gi
      s16x8 bh_, bl_;
      read_b(FRu + rp*P2STRIDE + PH0, lane, bh_, bl_);
      aR  = MFMA16(Ahh[0], bh_, aR);  aR  = MFMA16(Ahh[0], bl_, aR);  aR  = MFMA16(Ahl[0], bh_, aR);
      aZ  = MFMA16(Ahh[1], bh_, aZ);  aZ  = MFMA16(Ahh[1], bl_, aZ);  aZ  = MFMA16(Ahl[1], bh_, aZ);
      aNh = MFMA16(Ahh[2], bh_, aNh); aNh = MFMA16(Ahh[2], bl_, aNh); aNh = MFMA16(Ahl[2], bh_, aNh);
      combine_write2<4>(aR, aZ, aNi, aNh, hprev, FRu + par*P2STRIDE + PH0, jbase, 16, lane);
    }
    gR0 = gR1; gZ0 = gZ1; gN0 = gN1;
    gR1 = gR2; gZ1 = gZ2; gN1 = gN2;
    soft_barrier();
  }
}

template<int DIN, int DH>
__device__ __forceinline__ void wave_mid(
    const float* __restrict__ Wih, const float* __restrict__ Whh,
    const float* __restrict__ bih, const float* __restrict__ bhh,
    int jbase, int xc, int hc, int s0, int s1,
    u16* FRu, int b0, int lane)
{
  const int nrow = (DH - jbase) < 16 ? (DH - jbase) : 16;
  s16x8 Axh[3], Axl[3], Ahh[3], Ahl[3];
#pragma unroll
  for (int g = 0; g < 3; ++g) {
    load_wfrag(Wih, g*DH + jbase, nrow, DIN, 0, lane, Axh[g], Axl[g]);
    load_wfrag(Whh, g*DH + jbase, nrow, DH, 0, lane, Ahh[g], Ahl[g]);
  }
  const int q = lane >> 4;
  f32x4 cR, cZ, cNi, cNh;
#pragma unroll
  for (int i = 0; i < 4; ++i) {
    int lr = q*4 + i;
    int j = jbase + lr;
    bool jr = lr < nrow;
    cR[i]  = jr ? bih[j] + bhh[j] : 0.f;
    cZ[i]  = jr ? bih[DH+j] + bhh[DH+j] : 0.f;
    cNi[i] = jr ? bih[2*DH+j] : 0.f;
    cNh[i] = jr ? bhh[2*DH+j] : 0.f;
  }
  float hprev[4] = {0.f,0.f,0.f,0.f};

  for (int s = 0; s < NSTEP2; ++s) {
    const int par = s & 1, rp = par ^ 1;
    if (s >= s0 && s <= s1) {
      f32x4 aR = cR, aZ = cZ, aNi = cNi, aNh = cNh;
      s16x8 bh_, bl_;
      read_b(FRu + rp*P2STRIDE + xc, lane, bh_, bl_);
      aR  = MFMA16(Axh[0], bh_, aR);  aR  = MFMA16(Axh[0], bl_, aR);  aR  = MFMA16(Axl[0], bh_, aR);
      aZ  = MFMA16(Axh[1], bh_, aZ);  aZ  = MFMA16(Axh[1], bl_, aZ);  aZ  = MFMA16(Axl[1], bh_, aZ);
      aNi = MFMA16(Axh[2], bh_, aNi); aNi = MFMA16(Axh[2], bl_, aNi); aNi = MFMA16(Axl[2], bh_, aNi);
      read_b(FRu + rp*P2STRIDE + hc, lane, bh_, bl_);
      aR  = MFMA16(Ahh[0], bh_, aR);  aR  = MFMA16(Ahh[0], bl_, aR);  aR  = MFMA16(Ahl[0], bh_, aR);
      aZ  = MFMA16(Ahh[1], bh_, aZ);  aZ  = MFMA16(Ahh[1], bl_, aZ);  aZ  = MFMA16(Ahl[1], bh_, aZ);
      aNh = MFMA16(Ahh[2], bh_, aNh); aNh = MFMA16(Ahh[2], bl_, aNh); aNh = MFMA16(Ahl[2], bh_, aNh);
      combine_write2<4>(aR, aZ, aNi, aNh, hprev, FRu + par*P2STRIDE + hc, jbase, nrow, lane);
    }
    soft_barrier();
  }
}

__device__ __forceinline__ void wave_out2(
    const float* __restrict__ OW, const float* __restrict__ OBb,
    u16* FRu, float* __restrict__ out, int b0, int lane)
{
  s16x8 Oh[4], Ol[4];
  f32x4 cO[4];
  const int q = lane >> 4, bb = lane & 15;
#pragma unroll
  for (int t4 = 0; t4 < 4; ++t4) {
    load_wfrag(OW, t4*16, 16, 32, 0, lane, Oh[t4], Ol[t4]);
#pragma unroll
    for (int i = 0; i < 4; ++i) cO[t4][i] = OBb[t4*16 + q*4 + i];
  }
  float* ob = out + ((size_t)(b0 + (bb & 3))*NT)*DD + q*4;   // t=0 base for this lane

  for (int s = 0; s < NSTEP2; ++s) {
    const int rp = (s & 1) ^ 1;
    if (s >= 5) {
      s16x8 bh_, bl_;
      read_b(FRu + rp*P2STRIDE + PH4, lane, bh_, bl_);
#pragma unroll
      for (int t4 = 0; t4 < 4; ++t4) {
        f32x4 a_ = cO[t4];
        a_ = MFMA16(Oh[t4], bh_, a_); a_ = MFMA16(Oh[t4], bl_, a_); a_ = MFMA16(Ol[t4], bh_, a_);
        if (bb < 4) *(f32x4*)(ob + t4*16) = a_;   // direct C-frag store (64B segments)
      }
      ob += DD;
    }
    soft_barrier();
  }
}

__global__ __launch_bounds__(NTH, 2)
void gru_rec(const float* __restrict__ gi,
             const float* __restrict__ whh0, const float* __restrict__ bhh0,
             const float* __restrict__ wih1, const float* __restrict__ whh1, const float* __restrict__ bih1, const float* __restrict__ bhh1,
             const float* __restrict__ wih2, const float* __restrict__ whh2, const float* __restrict__ bih2, const float* __restrict__ bhh2,
             const float* __restrict__ wih3, const float* __restrict__ whh3, const float* __restrict__ bih3, const float* __restrict__ bhh3,
             const float* __restrict__ wih4, const float* __restrict__ whh4, const float* __restrict__ bih4, const float* __restrict__ bhh4,
             const float* __restrict__ out_w, const float* __restrict__ out_b,
             float* __restrict__ out)
{
  __shared__ __align__(16) u16 FRu[FRTOT2];
  const int tid = threadIdx.x;
  const int w = tid >> 6, lane = tid & 63;
  const int b0 = blockIdx.x * 4;

  for (int i = tid; i < FRTOT2; i += NTH) FRu[i] = 0;
  __syncthreads();

  if (w == 0)
    wave_l0(whh0, bhh0, gi,  0, FRu, b0, lane);
  else if (w == 1)
    wave_l0(whh0, bhh0, gi, 16, FRu, b0, lane);
  else if (w == 2)
    wave_mid<32,16>(wih1,whh1,bih1,bhh1,  0, PH0, PH1, 1, 512, FRu, b0, lane);
  else if (w == 4)
    wave_mid<16, 8>(wih2,whh2,bih2,bhh2,  0, PH1, PH2, 2, 513, FRu, b0, lane);
  else if (w == 5)
    wave_mid< 8,16>(wih3,whh3,bih3,bhh3,  0, PH2, PH3, 3, 514, FRu, b0, lane);
  else if (w == 3)
    wave_mid<16,32>(wih4,whh4,bih4,bhh4,  0, PH3, PH4, 4, 515, FRu, b0, lane);
  else if (w == 6)
    wave_mid<16,32>(wih4,whh4,bih4,bhh4, 16, PH3, PH4, 4, 515, FRu, b0, lane);
  else
    wave_out2(out_w, out_b, FRu, out, b0, lane);
}

// =====================================================================
// Fallback: round-3 kernel (used only if ws_size is too small for gi0)
// =====================================================================
__device__ __forceinline__ void combine_write(
    f32x4 aR, f32x4 aZ, f32x4 aNi, f32x4 aNh,
    float (&hprev)[4], u16* hdst_base, int jbase, int nrow, int lane)
{
  const int bb = lane & 15, q = lane >> 4;
  float hv[4];
#pragma unroll
  for (int i = 0; i < 4; ++i) {
    float rr = sigf(aR[i]);
    float zz = sigf(aZ[i]);
    float nn = tanhf2(aNi[i] + rr*aNh[i]);
    hv[i] = (1.0f - zz)*nn + zz*hprev[i];
    hprev[i] = hv[i];
  }
  if (bb < 8 && q*4 < nrow) {
    const int j = jbase + q*4;
    const int kb = j >> 3, e = j & 7;
    s16x4 hh, ll;
#pragma unroll
    for (int i = 0; i < 4; ++i) {
      u16 h = f2bf(hv[i]);
      hh[i] = (short)h;
      ll[i] = (short)f2bf(hv[i] - bf2f(h));
    }
    u16* dst = hdst_base + kb*256 + bb*8 + e;
    *(s16x4*)dst = hh;
    *(s16x4*)(dst + 128) = ll;
  }
}

__device__ __forceinline__ void write_x(u16* FRu, int par, int w, int lane, float v)
{
  const int d = lane;
  const int chunk = d >> 5, kb = (d >> 3) & 3, e = d & 7;
  u16 h = f2bf(v);
  u16 l2 = f2bf(v - bf2f(h));
  u16* p = FRu + par*PSTRIDE + XIN0 + chunk*CHUNK + kb*256 + w*8 + e;
  p[0] = h; p[128] = l2;
}

template<int DIN, int DH, int NXC>
__device__ __forceinline__ void wave_gru_fb(
    const float* __restrict__ Wih, const float* __restrict__ Whh,
    const float* __restrict__ bih, const float* __restrict__ bhh,
    int jbase, int xc, int hc, int s0, int s1,
    u16* FRu, float* OST,
    const float* __restrict__ X, const float* __restrict__ Mm, const float* __restrict__ Ll,
    float* __restrict__ out, int b0, int w, int lane)
{
  const int nrow = (DH - jbase) < 16 ? (DH - jbase) : 16;
  s16x8 Axh[3][NXC], Axl[3][NXC], Ahh[3], Ahl[3];
#pragma unroll
  for (int g = 0; g < 3; ++g) {
#pragma unroll
    for (int c = 0; c < NXC; ++c)
      load_wfrag(Wih, g*DH + jbase, nrow, DIN, c*32, lane, Axh[g][c], Axl[g][c]);
    load_wfrag(Whh, g*DH + jbase, nrow, DH, 0, lane, Ahh[g], Ahl[g]);
  }
  f32x4 cR, cZ, cNi, cNh;
  {
    const int q = lane >> 4;
#pragma unroll
    for (int i = 0; i < 4; ++i) {
      int lr = q*4 + i;
      int j = jbase + lr;
      bool jr = lr < nrow;
      cR[i]  = jr ? bih[j] + bhh[j] : 0.f;
      cZ[i]  = jr ? bih[DH+j] + bhh[DH+j] : 0.f;
      cNi[i] = jr ? bih[2*DH+j] : 0.f;
      cNh[i] = jr ? bhh[2*DH+j] : 0.f;
    }
  }
  float hprev[4] = {0.f, 0.f, 0.f, 0.f};

  const size_t gbase = ((size_t)(b0 + w))*((size_t)NT*DD) + lane;
  float rx = X[gbase], rm = Mm[gbase], rl = Ll[gbase];
  write_x(FRu, 1, w, lane, rx*rm + rl*(1.0f - rm));
  rx = X[gbase + DD]; rm = Mm[gbase + DD]; rl = Ll[gbase + DD];
  __syncthreads();

  for (int s = 0; s < NSTEP_FB; ++s) {
    const int par = s & 1, rp = par ^ 1;
    float nx = 0.f, nm = 0.f, nl = 0.f;
    if (s <= 509) {
      size_t g = gbase + (size_t)(s+2)*DD;
      nx = X[g]; nm = Mm[g]; nl = Ll[g];
    }
    f32x4 aR = cR, aZ = cZ, aNi = cNi, aNh = cNh;
    const bool run = (s >= s0) && (s <= s1);
    if (run) {
      const u16* RB = FRu + rp*PSTRIDE;
      s16x8 bh_, bl_;
#pragma unroll
      for (int c = 0; c < NXC; ++c) {
        read_b(RB + xc + c*CHUNK, lane, bh_, bl_);
        aR  = MFMA16(Axh[0][c], bh_, aR);  aR  = MFMA16(Axh[0][c], bl_, aR);  aR  = MFMA16(Axl[0][c], bh_, aR);
        aZ  = MFMA16(Axh[1][c], bh_, aZ);  aZ  = MFMA16(Axh[1][c], bl_, aZ);  aZ  = MFMA16(Axl[1][c], bh_, aZ);
        aNi = MFMA16(Axh[2][c], bh_, aNi); aNi = MFMA16(Axh[2][c], bl_, aNi); aNi = MFMA16(Axl[2][c], bh_, aNi);
      }
      read_b(RB + hc, lane, bh_, bl_);
      aR  = MFMA16(Ahh[0], bh_, aR);  aR  = MFMA16(Ahh[0], bl_, aR);  aR  = MFMA16(Ahl[0], bh_, aR);
      aZ  = MFMA16(Ahh[1], bh_, aZ);  aZ  = MFMA16(Ahh[1], bl_, aZ);  aZ  = MFMA16(Ahl[1], bh_, aZ);
      aNh = MFMA16(Ahh[2], bh_, aNh); aNh = MFMA16(Ahh[2], bl_, aNh); aNh = MFMA16(Ahl[2], bh_, aNh);
    }
    __syncthreads();

    if (run)
      combine_write(aR, aZ, aNi, aNh, hprev, FRu + par*PSTRIDE + hc, jbase, nrow, lane);
    if (s >= 5)
      out[((size_t)(b0 + w)*NT + (s-5))*DD + lane] = OST[w*65 + lane];
    if (s <= 510) write_x(FRu, par, w, lane, rx*rm + rl*(1.0f - rm));
    rx = nx; rm = nm; rl = nl;
    __syncthreads();
  }
}

__device__ __forceinline__ void wave_out_fb(
    const float* __restrict__ OW, const float* __restrict__ OBb,
    u16* FRu, float* OST,
    const float* __restrict__ X, const float* __restrict__ Mm, const float* __restrict__ Ll,
    float* __restrict__ out, int b0, int w, int lane)
{
  s16x8 Oh[4], Ol[4];
  f32x4 cO[4];
#pragma unroll
  for (int t4 = 0; t4 < 4; ++t4) {
    load_wfrag(OW, t4*16, 16, 32, 0, lane, Oh[t4], Ol[t4]);
#pragma unroll
    for (int i = 0; i < 4; ++i) cO[t4][i] = OBb[t4*16 + (lane>>4)*4 + i];
  }
  const size_t gbase = ((size_t)(b0 + w))*((size_t)NT*DD) + lane;
  float rx = X[gbase], rm = Mm[gbase], rl = Ll[gbase];
  write_x(FRu, 1, w, lane, rx*rm + rl*(1.0f - rm));
  rx = X[gbase + DD]; rm = Mm[gbase + DD]; rl = Ll[gbase + DD];
  __syncthreads();

  for (int s = 0; s < NSTEP_FB; ++s) {
    const int par = s & 1, rp = par ^ 1;
    float nx = 0.f, nm = 0.f, nl = 0.f;
    if (s <= 509) { size_t g = gbase + (size_t)(s+2)*DD; nx = X[g]; nm = Mm[g]; nl = Ll[g]; }
    if (s >= 5) {
      s16x8 bh_, bl_;
      read_b(FRu + rp*PSTRIDE + H4C, lane, bh_, bl_);
      const int bb = lane & 15, q = lane >> 4;
#pragma unroll
      for (int t4 = 0; t4 < 4; ++t4) {
        f32x4 a_ = cO[t4];
        a_ = MFMA16(Oh[t4], bh_, a_); a_ = MFMA16(Oh[t4], bl_, a_); a_ = MFMA16(Ol[t4], bh_, a_);
        if (bb < 8) {
#pragma unroll
          for (int i = 0; i < 4; ++i) OST[bb*65 + t4*16 + q*4 + i] = a_[i];
        }
      }
    }
    __syncthreads();
    if (s >= 5)
      out[((size_t)(b0 + w)*NT + (s-5))*DD + lane] = OST[w*65 + lane];
    if (s <= 510) write_x(FRu, par, w, lane, rx*rm + rl*(1.0f - rm));
    rx = nx; rm = nm; rl = nl;
    __syncthreads();
  }
}

__global__ __launch_bounds__(NTH, 1)
void gru_mfma(const float* __restrict__ X, const float* __restrict__ M, const float* __restrict__ L,
              const float* __restrict__ wih0, const float* __restrict__ whh0, const float* __restrict__ bih0, const float* __restrict__ bhh0,
              const float* __restrict__ wih1, const float* __restrict__ whh1, const float* __restrict__ bih1, const float* __restrict__ bhh1,
              const float* __restrict__ wih2, const float* __restrict__ whh2, const float* __restrict__ bih2, const float* __restrict__ bhh2,
              const float* __restrict__ wih3, const float* __restrict__ whh3, const float* __restrict__ bih3, const float* __restrict__ bhh3,
              const float* __restrict__ wih4, const float* __restrict__ whh4, const float* __restrict__ bih4, const float* __restrict__ bhh4,
              const float* __restrict__ out_w, const float* __restrict__ out_b,
              float* __restrict__ out)
{
  __shared__ __align__(16) u16 FRu[FRTOT];
  __shared__ float OST[8*65];
  const int tid = threadIdx.x;
  const int w = tid >> 6, lane = tid & 63;
  const int b0 = blockIdx.x * 8;

  for (int i = tid; i < FRTOT; i += NTH) FRu[i] = 0;
  for (int i = tid; i < 8*65; i += NTH) OST[i] = 0.f;
  __syncthreads();

  if (w == 0)
    wave_gru_fb<64,32,2>(wih0,whh0,bih0,bhh0,  0, XIN0, H0C, 0, 511, FRu, OST, X,M,L, out, b0, w, lane);
  else if (w == 1)
    wave_gru_fb<64,32,2>(wih0,whh0,bih0,bhh0, 16, XIN0, H0C, 0, 511, FRu, OST, X,M,L, out, b0, w, lane);
  else if (w == 2)
    wave_gru_fb<32,16,1>(wih1,whh1,bih1,bhh1,  0, H0C,  H1C, 1, 512, FRu, OST, X,M,L, out, b0, w, lane);
  else if (w == 4)
    wave_gru_fb<16, 8,1>(wih2,whh2,bih2,bhh2,  0, H1C,  H2C, 2, 513, FRu, OST, X,M,L, out, b0, w, lane);
  else if (w == 5)
    wave_gru_fb< 8,16,1>(wih3,whh3,bih3,bhh3,  0, H2C,  H3C, 3, 514, FRu, OST, X,M,L, out, b0, w, lane);
  else if (w == 3)
    wave_gru_fb<16,32,1>(wih4,whh4,bih4,bhh4,  0, H3C,  H4C, 4, 515, FRu, OST, X,M,L, out, b0, w, lane);
  else if (w == 6)
    wave_gru_fb<16,32,1>(wih4,whh4,bih4,bhh4, 16, H3C,  H4C, 4, 515, FRu, OST, X,M,L, out, b0, w, lane);
  else
    wave_out_fb(out_w, out_b, FRu, OST, X,M,L, out, b0, w, lane);
}

extern "C" void kernel_launch(void* const* d_in, const int* in_sizes, int n_in,
                              void* d_out, int out_size, void* d_ws, size_t ws_size,
                              hipStream_t stream)
{
  const float* X  = (const float*)d_in[0];
  const float* M  = (const float*)d_in[1];
  const float* L  = (const float*)d_in[2];
  const float* wp[20];
  for (int i = 0; i < 20; ++i) wp[i] = (const float*)d_in[3 + i];
  const float* ow = (const float*)d_in[23];
  const float* ob = (const float*)d_in[24];
  float* out = (float*)d_out;

  const size_t gi_bytes = (size_t)2048 * NT * 96 * sizeof(float);  // 402,653,184
  if (ws_size >= gi_bytes) {
    float* gi = (float*)d_ws;
    gi0_gemm<<<dim3(2048*4), dim3(256), 0, stream>>>(X, M, L, wp[0], wp[2], wp[3], gi);
    gru_rec<<<dim3(512), dim3(NTH), 0, stream>>>(
        gi, wp[1], wp[3],
        wp[4], wp[5], wp[6], wp[7],
        wp[8], wp[9], wp[10], wp[11],
        wp[12], wp[13], wp[14], wp[15],
        wp[16], wp[17], wp[18], wp[19],
        ow, ob, out);
  } else {
    gru_mfma<<<dim3(256), dim3(NTH), 0, stream>>>(
        X, M, L,
        wp[0], wp[1], wp[2], wp[3],
        wp[4], wp[5], wp[6], wp[7],
        wp[8], wp[9], wp[10], wp[11],
        wp[12], wp[13], wp[14], wp[15],
        wp[16], wp[17], wp[18], wp[19],
        ow, ob, out);
  }
}

// Round 9
// 861.424 us; speedup vs baseline: 1.4916x; 1.4916x over previous
//
#include <hip/hip_runtime.h>

typedef short s16x8 __attribute__((ext_vector_type(8)));
typedef short s16x4 __attribute__((ext_vector_type(4)));
typedef float f32x4 __attribute__((ext_vector_type(4)));
typedef unsigned int u32;
typedef unsigned short u16;

#define NT 512
#define DD 64
#define NTH 512

#define CHUNK 1024

// ---------- recurrent kernel LDS (5 h-chunks per parity) ----------
#define P2STRIDE (5*CHUNK)
#define PH0 0
#define PH1 CHUNK
#define PH2 (2*CHUNK)
#define PH3 (3*CHUNK)
#define PH4 (4*CHUNK)
#define FRTOT2 (2*P2STRIDE)   // 10240 u16 = 20 KB
#define NSTEP2 517            // 512 + 5 pipeline stages

// ---------- fallback (round-3) LDS ----------
#define PSTRIDE (7*CHUNK)
#define XIN0 0
#define H0C (2*CHUNK)
#define H1C (3*CHUNK)
#define H2C (4*CHUNK)
#define H3C (5*CHUNK)
#define H4C (6*CHUNK)
#define FRTOT (2*PSTRIDE)
#define NSTEP_FB 517

#define MFMA16(A,B,C) __builtin_amdgcn_mfma_f32_16x16x32_bf16(A,B,C,0,0,0)

__device__ __forceinline__ float sigf(float x){ return 1.0f/(1.0f+__expf(-x)); }
__device__ __forceinline__ float tanhf2(float x){ return 2.0f/(1.0f+__expf(-2.0f*x)) - 1.0f; }

__device__ __forceinline__ u16 f2bf(float f) {
  u32 u = __builtin_bit_cast(u32, f);
  return (u16)((u + 0x7fffu + ((u >> 16) & 1u)) >> 16);
}
__device__ __forceinline__ float bf2f(u16 h) {
  u32 u = ((u32)h) << 16;
  return __builtin_bit_cast(float, u);
}

// barrier WITHOUT the vmcnt(0) drain: LDS visibility only (global ops drain at use)
__device__ __forceinline__ void soft_barrier() {
  asm volatile("s_waitcnt lgkmcnt(0)" ::: "memory");
  __builtin_amdgcn_s_barrier();
  asm volatile("" ::: "memory");
}

__device__ __forceinline__ u32 cvtpk_bf16(float a, float b) {
  u32 r;
  asm("v_cvt_pk_bf16_f32 %0, %1, %2" : "=v"(r) : "v"(a), "v"(b));
  return r;
}

// A-fragment (standard hi/lo pair): lane holds A[row0+(lane&15)][kbase+(lane>>4)*8+e]
__device__ __forceinline__ void load_wfrag(const float* __restrict__ W, int row0, int nrow, int din,
                                           int kbase, int lane, s16x8& hi, s16x8& lo)
{
  const int m = lane & 15, kb = lane >> 4;
#pragma unroll
  for (int e = 0; e < 8; ++e) {
    int k = kbase + kb*8 + e;
    float v = (m < nrow && k < din) ? W[(size_t)(row0 + m)*din + k] : 0.0f;
    u16 h = f2bf(v);
    hi[e] = (short)h;
    lo[e] = (short)f2bf(v - bf2f(h));
  }
}

// Packed A-fragment for real K <= 16: lane-groups q=0,1 hold hi[k=(q&1)*8+e],
// q=2,3 hold lo[k=(q&1)*8+e]. One fragment replaces the (hi,lo) pair.
__device__ __forceinline__ void load_wfrag_pk(const float* __restrict__ W, int row0, int nrow,
                                              int stride, int KR, int lane, s16x8& A1)
{
  const int m = lane & 15, q = lane >> 4;
  const bool lohalf = q >= 2;
  const int kb = (q & 1) * 8;
#pragma unroll
  for (int e = 0; e < 8; ++e) {
    int k = kb + e;
    float v = (m < nrow && k < KR) ? W[(size_t)(row0 + m)*stride + k] : 0.0f;
    u16 h = f2bf(v);
    A1[e] = (short)(lohalf ? f2bf(v - bf2f(h)) : h);
  }
}

// B-fragment read (standard): hi at +0, lo at +128 within each 256-u16 k-block
__device__ __forceinline__ void read_b(const u16* base, int lane, s16x8& hi, s16x8& lo)
{
  const int off = ((lane >> 4) << 8) + ((lane & 15) << 3);
  hi = *(const s16x8*)(base + off);
  lo = *(const s16x8*)(base + off + 128);
}

// Packed B-fragment read for real K <= 16 against the SAME storage layout:
// b1 = [hi(k0..15) | lo(k0..15)], b2 = halves crossed = addr ^ 128.
// MFMA(A1,b1)+MFMA(A1,b2) = full (Ah+Al)(Bh+Bl) in 2 MFMAs.
__device__ __forceinline__ void read_b_pk(const u16* base, int lane, s16x8& b1, s16x8& b2)
{
  const int q = lane >> 4;
  const int off1 = ((q & 1) << 8) + ((q >> 1) << 7) + ((lane & 15) << 3);
  b1 = *(const s16x8*)(base + off1);
  b2 = *(const s16x8*)(base + (off1 ^ 128));
}

// gate combine + h write (cvt_pk packing); stores batch columns bb < 8
__device__ __forceinline__ void combine_write2(
    f32x4 aR, f32x4 aZ, f32x4 aNi, f32x4 aNh,
    float (&hprev)[4], u16* hdst_base, int jbase, int nrow, int lane)
{
  const int bb = lane & 15, q = lane >> 4;
  float hv[4];
#pragma unroll
  for (int i = 0; i < 4; ++i) {
    float rr = sigf(aR[i]);
    float zz = sigf(aZ[i]);
    float nn = tanhf2(aNi[i] + rr*aNh[i]);
    hv[i] = (1.0f - zz)*nn + zz*hprev[i];
    hprev[i] = hv[i];
  }
  if (bb < 8 && q*4 < nrow) {
    const int j = jbase + q*4;
    u16* dst = hdst_base + ((j >> 3) << 8) + bb*8 + (j & 7);
    u32 p01 = cvtpk_bf16(hv[0], hv[1]);
    u32 p23 = cvtpk_bf16(hv[2], hv[3]);
    float h0 = __builtin_bit_cast(float, p01 << 16);
    float h1 = __builtin_bit_cast(float, p01 & 0xffff0000u);
    float h2 = __builtin_bit_cast(float, p23 << 16);
    float h3 = __builtin_bit_cast(float, p23 & 0xffff0000u);
    u32 q01 = cvtpk_bf16(hv[0]-h0, hv[1]-h1);
    u32 q23 = cvtpk_bf16(hv[2]-h2, hv[3]-h3);
    uint2 hp_; hp_.x = p01; hp_.y = p23;
    uint2 lp_; lp_.x = q01; lp_.y = q23;
    *(uint2*)dst = hp_;
    *(uint2*)(dst + 128) = lp_;
  }
}

// =====================================================================
// Phase 1: gi0[b][t][96] = Wih0 @ x_imp(b,t) + bih0 (+bhh0 for r,z rows)
// =====================================================================
__global__ __launch_bounds__(256)
void gi0_gemm(const float* __restrict__ X, const float* __restrict__ M, const float* __restrict__ L,
              const float* __restrict__ wih0, const float* __restrict__ bih0,
              const float* __restrict__ bhh0,
              float* __restrict__ gi)
{
  __shared__ u32 xs[128*65];
  const int tid = threadIdx.x;
  const int wv = tid >> 6, lane = tid & 63;
  const int q = lane >> 4;
  const int b = blockIdx.x >> 2;
  const int t0 = (blockIdx.x & 3) * 128;
  const size_t base = ((size_t)b*NT + t0)*DD;

  for (int i = tid; i < 128*64; i += 256) {
    float x = X[base+i], m = M[base+i], l = L[base+i];
    float v = x*m + l*(1.0f - m);
    u16 h = f2bf(v);
    u16 lo2 = f2bf(v - bf2f(h));
    const int t = i >> 6, d = i & 63;
    xs[t*65 + d] = (u32)h | ((u32)lo2 << 16);
  }

  s16x8 Ah[6][2], Al[6][2];
  f32x4 cb[6];
#pragma unroll
  for (int tile = 0; tile < 6; ++tile) {
#pragma unroll
    for (int c = 0; c < 2; ++c)
      load_wfrag(wih0, tile*16, 16, 64, c*32, lane, Ah[tile][c], Al[tile][c]);
#pragma unroll
    for (int i = 0; i < 4; ++i) {
      int row = tile*16 + q*4 + i;
      float bv = bih0[row];
      if (tile < 4) bv += bhh0[row];
      cb[tile][i] = bv;
    }
  }
  __syncthreads();

#pragma unroll
  for (int g2 = 0; g2 < 2; ++g2) {
    const int tloc = g2*64 + wv*16 + (lane & 15);
    s16x8 Bh[2], Bl[2];
#pragma unroll
    for (int c = 0; c < 2; ++c) {
      const u32* p = &xs[tloc*65 + c*32 + q*8];
#pragma unroll
      for (int e = 0; e < 8; ++e) {
        u32 v = p[e];
        Bh[c][e] = (short)(v & 0xffffu);
        Bl[c][e] = (short)(v >> 16);
      }
    }
    float* gp = gi + ((size_t)b*NT + t0 + tloc)*96 + q*4;
#pragma unroll
    for (int tile = 0; tile < 6; ++tile) {
      f32x4 acc = cb[tile];
#pragma unroll
      for (int c = 0; c < 2; ++c) {
        acc = MFMA16(Ah[tile][c], Bh[c], acc);
        acc = MFMA16(Ah[tile][c], Bl[c], acc);
        acc = MFMA16(Al[tile][c], Bh[c], acc);
      }
      *(f32x4*)(gp + tile*16) = acc;
    }
  }
}

// =====================================================================
// Phase 2: recurrent kernel — R5 structure (8 waves, BB=8, 1 block/CU),
// packed-K 2-MFMA for small-K groups, 2x unrolled static-parity loops.
// =====================================================================
__device__ __forceinline__ void wave_l0(
    const float* __restrict__ Whh, const float* __restrict__ bhh,
    const float* __restrict__ gi, int jbase,
    u16* FRu, int b0, int lane)
{
  s16x8 Ahh[3], Ahl[3];
#pragma unroll
  for (int g = 0; g < 3; ++g)
    load_wfrag(Whh, g*32 + jbase, 16, 32, 0, lane, Ahh[g], Ahl[g]);
  const int q = lane >> 4;
  f32x4 cNh;
#pragma unroll
  for (int i = 0; i < 4; ++i) cNh[i] = bhh[64 + jbase + q*4 + i];
  float hprev[4] = {0.f,0.f,0.f,0.f};

  const float* gb = gi + (size_t)(b0 + (lane & 7)) * ((size_t)NT*96) + jbase + q*4;
  f32x4 AR, AZ, AN, BR, BZ, BN;
  AR = *(const f32x4*)(gb);      AZ = *(const f32x4*)(gb+32);  AN = *(const f32x4*)(gb+64);
  BR = *(const f32x4*)(gb+96);   BZ = *(const f32x4*)(gb+128); BN = *(const f32x4*)(gb+160);

  for (int s = 0; s < NSTEP2; s += 2) {
    // ---- half 1: step s (even): rp=1, par=0 ----
    if (s < NT) {
      f32x4 aR = AR, aZ = AZ, aNi = AN, aNh = cNh;   // biases pre-folded in gi
      s16x8 bh_, bl_;
      read_b(FRu + P2STRIDE + PH0, lane, bh_, bl_);
      aR  = MFMA16(Ahh[0], bh_, aR);  aR  = MFMA16(Ahh[0], bl_, aR);  aR  = MFMA16(Ahl[0], bh_, aR);
      aZ  = MFMA16(Ahh[1], bh_, aZ);  aZ  = MFMA16(Ahh[1], bl_, aZ);  aZ  = MFMA16(Ahl[1], bh_, aZ);
      aNh = MFMA16(Ahh[2], bh_, aNh); aNh = MFMA16(Ahh[2], bl_, aNh); aNh = MFMA16(Ahl[2], bh_, aNh);
      combine_write2(aR, aZ, aNi, aNh, hprev, FRu + PH0, jbase, 16, lane);
    }
    if (s + 2 < NT) {
      const float* p = gb + (size_t)(s + 2)*96;
      AR = *(const f32x4*)(p); AZ = *(const f32x4*)(p+32); AN = *(const f32x4*)(p+64);
    }
    soft_barrier();
    // ---- half 2: step s+1 (odd): rp=0, par=1 ----
    if (s + 1 < NT) {
      f32x4 aR = BR, aZ = BZ, aNi = BN, aNh = cNh;
      s16x8 bh_, bl_;
      read_b(FRu + PH0, lane, bh_, bl_);
      aR  = MFMA16(Ahh[0], bh_, aR);  aR  = MFMA16(Ahh[0], bl_, aR);  aR  = MFMA16(Ahl[0], bh_, aR);
      aZ  = MFMA16(Ahh[1], bh_, aZ);  aZ  = MFMA16(Ahh[1], bl_, aZ);  aZ  = MFMA16(Ahl[1], bh_, aZ);
      aNh = MFMA16(Ahh[2], bh_, aNh); aNh = MFMA16(Ahh[2], bl_, aNh); aNh = MFMA16(Ahl[2], bh_, aNh);
      combine_write2(aR, aZ, aNi, aNh, hprev, FRu + P2STRIDE + PH0, jbase, 16, lane);
    }
    if (s + 3 < NT) {
      const float* p = gb + (size_t)(s + 3)*96;
      BR = *(const f32x4*)(p); BZ = *(const f32x4*)(p+32); BN = *(const f32x4*)(p+64);
    }
    soft_barrier();
  }
}

template<int DIN, int DH, bool PKX, bool PKH>
__device__ __forceinline__ void wave_mid_pk(
    const float* __restrict__ Wih, const float* __restrict__ Whh,
    const float* __restrict__ bih, const float* __restrict__ bhh,
    int jbase, int xc, int hc, int s0, int s1,
    u16* FRu, int lane)
{
  const int nrow = (DH - jbase) < 16 ? (DH - jbase) : 16;
  s16x8 Ax1[3], Axh[3], Axl[3], Ah1[3], Ahh[3], Ahl[3];
#pragma unroll
  for (int g = 0; g < 3; ++g) {
    if constexpr (PKX) load_wfrag_pk(Wih, g*DH + jbase, nrow, DIN, DIN, lane, Ax1[g]);
    else               load_wfrag(Wih, g*DH + jbase, nrow, DIN, 0, lane, Axh[g], Axl[g]);
    if constexpr (PKH) load_wfrag_pk(Whh, g*DH + jbase, nrow, DH, DH, lane, Ah1[g]);
    else               load_wfrag(Whh, g*DH + jbase, nrow, DH, 0, lane, Ahh[g], Ahl[g]);
  }
  const int q = lane >> 4;
  f32x4 cR, cZ, cNi, cNh;
#pragma unroll
  for (int i = 0; i < 4; ++i) {
    int lr = q*4 + i;
    int j = jbase + lr;
    bool jr = lr < nrow;
    cR[i]  = jr ? bih[j] + bhh[j] : 0.f;
    cZ[i]  = jr ? bih[DH+j] + bhh[DH+j] : 0.f;
    cNi[i] = jr ? bih[2*DH+j] : 0.f;
    cNh[i] = jr ? bhh[2*DH+j] : 0.f;
  }
  float hprev[4] = {0.f,0.f,0.f,0.f};

  auto body = [&](int st, const u16* R, u16* Wp) {
    if (st >= s0 && st <= s1) {
      f32x4 aR = cR, aZ = cZ, aNi = cNi, aNh = cNh;
      if constexpr (PKX) {
        s16x8 b1, b2;
        read_b_pk(R + xc, lane, b1, b2);
        aR  = MFMA16(Ax1[0], b1, aR);  aR  = MFMA16(Ax1[0], b2, aR);
        aZ  = MFMA16(Ax1[1], b1, aZ);  aZ  = MFMA16(Ax1[1], b2, aZ);
        aNi = MFMA16(Ax1[2], b1, aNi); aNi = MFMA16(Ax1[2], b2, aNi);
      } else {
        s16x8 bh_, bl_;
        read_b(R + xc, lane, bh_, bl_);
        aR  = MFMA16(Axh[0], bh_, aR);  aR  = MFMA16(Axh[0], bl_, aR);  aR  = MFMA16(Axl[0], bh_, aR);
        aZ  = MFMA16(Axh[1], bh_, aZ);  aZ  = MFMA16(Axh[1], bl_, aZ);  aZ  = MFMA16(Axl[1], bh_, aZ);
        aNi = MFMA16(Axh[2], bh_, aNi); aNi = MFMA16(Axh[2], bl_, aNi); aNi = MFMA16(Axl[2], bh_, aNi);
      }
      if constexpr (PKH) {
        s16x8 b1, b2;
        read_b_pk(R + hc, lane, b1, b2);
        aR  = MFMA16(Ah1[0], b1, aR);  aR  = MFMA16(Ah1[0], b2, aR);
        aZ  = MFMA16(Ah1[1], b1, aZ);  aZ  = MFMA16(Ah1[1], b2, aZ);
        aNh = MFMA16(Ah1[2], b1, aNh); aNh = MFMA16(Ah1[2], b2, aNh);
      } else {
        s16x8 bh_, bl_;
        read_b(R + hc, lane, bh_, bl_);
        aR  = MFMA16(Ahh[0], bh_, aR);  aR  = MFMA16(Ahh[0], bl_, aR);  aR  = MFMA16(Ahl[0], bh_, aR);
        aZ  = MFMA16(Ahh[1], bh_, aZ);  aZ  = MFMA16(Ahh[1], bl_, aZ);  aZ  = MFMA16(Ahl[1], bh_, aZ);
        aNh = MFMA16(Ahh[2], bh_, aNh); aNh = MFMA16(Ahh[2], bl_, aNh); aNh = MFMA16(Ahl[2], bh_, aNh);
      }
      combine_write2(aR, aZ, aNi, aNh, hprev, Wp + hc, jbase, nrow, lane);
    }
  };

  for (int s = 0; s < NSTEP2; s += 2) {
    body(s,     FRu + P2STRIDE, FRu);           // rp=1, par=0
    soft_barrier();
    body(s + 1, FRu,            FRu + P2STRIDE); // rp=0, par=1
    soft_barrier();
  }
}

__device__ __forceinline__ void wave_out2(
    const float* __restrict__ OW, const float* __restrict__ OBb,
    u16* FRu, float* __restrict__ out, int b0, int lane)
{
  s16x8 Oh[4], Ol[4];
  f32x4 cO[4];
  const int q = lane >> 4, bb = lane & 15;
#pragma unroll
  for (int t4 = 0; t4 < 4; ++t4) {
    load_wfrag(OW, t4*16, 16, 32, 0, lane, Oh[t4], Ol[t4]);
#pragma unroll
    for (int i = 0; i < 4; ++i) cO[t4][i] = OBb[t4*16 + q*4 + i];
  }
  float* ob = out + ((size_t)(b0 + (bb & 7))*NT)*DD + q*4;   // t=0 base for this lane

  auto emit = [&](int st, const u16* R) {
    if (st >= 5 && st <= 516) {
      s16x8 bh_, bl_;
      read_b(R + PH4, lane, bh_, bl_);
#pragma unroll
      for (int t4 = 0; t4 < 4; ++t4) {
        f32x4 a_ = cO[t4];
        a_ = MFMA16(Oh[t4], bh_, a_); a_ = MFMA16(Oh[t4], bl_, a_); a_ = MFMA16(Ol[t4], bh_, a_);
        if (bb < 8) *(f32x4*)(ob + t4*16) = a_;   // direct C-frag store (64B segments)
      }
      ob += DD;
    }
  };

  for (int s = 0; s < NSTEP2; s += 2) {
    emit(s,     FRu + P2STRIDE);   // rp=1
    soft_barrier();
    emit(s + 1, FRu);              // rp=0
    soft_barrier();
  }
}

__global__ __launch_bounds__(NTH, 1)
void gru_rec(const float* __restrict__ gi,
             const float* __restrict__ whh0, const float* __restrict__ bhh0,
             const float* __restrict__ wih1, const float* __restrict__ whh1, const float* __restrict__ bih1, const float* __restrict__ bhh1,
             const float* __restrict__ wih2, const float* __restrict__ whh2, const float* __restrict__ bih2, const float* __restrict__ bhh2,
             const float* __restrict__ wih3, const float* __restrict__ whh3, const float* __restrict__ bih3, const float* __restrict__ bhh3,
             const float* __restrict__ wih4, const float* __restrict__ whh4, const float* __restrict__ bih4, const float* __restrict__ bhh4,
             const float* __restrict__ out_w, const float* __restrict__ out_b,
             float* __restrict__ out)
{
  __shared__ __align__(16) u16 FRu[FRTOT2];
  const int tid = threadIdx.x;
  const int w = tid >> 6, lane = tid & 63;
  const int b0 = blockIdx.x * 8;

  for (int i = tid; i < FRTOT2; i += NTH) FRu[i] = 0;
  __syncthreads();

  if (w == 0)
    wave_l0(whh0, bhh0, gi,  0, FRu, b0, lane);
  else if (w == 1)
    wave_l0(whh0, bhh0, gi, 16, FRu, b0, lane);
  else if (w == 2)
    wave_mid_pk<32,16,false,true >(wih1,whh1,bih1,bhh1,  0, PH0, PH1, 1, 512, FRu, lane);
  else if (w == 4)
    wave_mid_pk<16, 8,true ,true >(wih2,whh2,bih2,bhh2,  0, PH1, PH2, 2, 513, FRu, lane);
  else if (w == 5)
    wave_mid_pk< 8,16,true ,true >(wih3,whh3,bih3,bhh3,  0, PH2, PH3, 3, 514, FRu, lane);
  else if (w == 3)
    wave_mid_pk<16,32,true ,false>(wih4,whh4,bih4,bhh4,  0, PH3, PH4, 4, 515, FRu, lane);
  else if (w == 6)
    wave_mid_pk<16,32,true ,false>(wih4,whh4,bih4,bhh4, 16, PH3, PH4, 4, 515, FRu, lane);
  else
    wave_out2(out_w, out_b, FRu, out, b0, lane);
}

// =====================================================================
// Fallback: round-3 kernel (used only if ws_size is too small for gi0)
// =====================================================================
__device__ __forceinline__ void combine_write(
    f32x4 aR, f32x4 aZ, f32x4 aNi, f32x4 aNh,
    float (&hprev)[4], u16* hdst_base, int jbase, int nrow, int lane)
{
  const int bb = lane & 15, q = lane >> 4;
  float hv[4];
#pragma unroll
  for (int i = 0; i < 4; ++i) {
    float rr = sigf(aR[i]);
    float zz = sigf(aZ[i]);
    float nn = tanhf2(aNi[i] + rr*aNh[i]);
    hv[i] = (1.0f - zz)*nn + zz*hprev[i];
    hprev[i] = hv[i];
  }
  if (bb < 8 && q*4 < nrow) {
    const int j = jbase + q*4;
    const int kb = j >> 3, e = j & 7;
    s16x4 hh, ll;
#pragma unroll
    for (int i = 0; i < 4; ++i) {
      u16 h = f2bf(hv[i]);
      hh[i] = (short)h;
      ll[i] = (short)f2bf(hv[i] - bf2f(h));
    }
    u16* dst = hdst_base + kb*256 + bb*8 + e;
    *(s16x4*)dst = hh;
    *(s16x4*)(dst + 128) = ll;
  }
}

__device__ __forceinline__ void write_x(u16* FRu, int par, int w, int lane, float v)
{
  const int d = lane;
  const int chunk = d >> 5, kb = (d >> 3) & 3, e = d & 7;
  u16 h = f2bf(v);
  u16 l2 = f2bf(v - bf2f(h));
  u16* p = FRu + par*PSTRIDE + XIN0 + chunk*CHUNK + kb*256 + w*8 + e;
  p[0] = h; p[128] = l2;
}

template<int DIN, int DH, int NXC>
__device__ __forceinline__ void wave_gru_fb(
    const float* __restrict__ Wih, const float* __restrict__ Whh,
    const float* __restrict__ bih, const float* __restrict__ bhh,
    int jbase, int xc, int hc, int s0, int s1,
    u16* FRu, float* OST,
    const float* __restrict__ X, const float* __restrict__ Mm, const float* __restrict__ Ll,
    float* __restrict__ out, int b0, int w, int lane)
{
  const int nrow = (DH - jbase) < 16 ? (DH - jbase) : 16;
  s16x8 Axh[3][NXC], Axl[3][NXC], Ahh[3], Ahl[3];
#pragma unroll
  for (int g = 0; g < 3; ++g) {
#pragma unroll
    for (int c = 0; c < NXC; ++c)
      load_wfrag(Wih, g*DH + jbase, nrow, DIN, c*32, lane, Axh[g][c], Axl[g][c]);
    load_wfrag(Whh, g*DH + jbase, nrow, DH, 0, lane, Ahh[g], Ahl[g]);
  }
  f32x4 cR, cZ, cNi, cNh;
  {
    const int q = lane >> 4;
#pragma unroll
    for (int i = 0; i < 4; ++i) {
      int lr = q*4 + i;
      int j = jbase + lr;
      bool jr = lr < nrow;
      cR[i]  = jr ? bih[j] + bhh[j] : 0.f;
      cZ[i]  = jr ? bih[DH+j] + bhh[DH+j] : 0.f;
      cNi[i] = jr ? bih[2*DH+j] : 0.f;
      cNh[i] = jr ? bhh[2*DH+j] : 0.f;
    }
  }
  float hprev[4] = {0.f, 0.f, 0.f, 0.f};

  const size_t gbase = ((size_t)(b0 + w))*((size_t)NT*DD) + lane;
  float rx = X[gbase], rm = Mm[gbase], rl = Ll[gbase];
  write_x(FRu, 1, w, lane, rx*rm + rl*(1.0f - rm));
  rx = X[gbase + DD]; rm = Mm[gbase + DD]; rl = Ll[gbase + DD];
  __syncthreads();

  for (int s = 0; s < NSTEP_FB; ++s) {
    const int par = s & 1, rp = par ^ 1;
    float nx = 0.f, nm = 0.f, nl = 0.f;
    if (s <= 509) {
      size_t g = gbase + (size_t)(s+2)*DD;
      nx = X[g]; nm = Mm[g]; nl = Ll[g];
    }
    f32x4 aR = cR, aZ = cZ, aNi = cNi, aNh = cNh;
    const bool run = (s >= s0) && (s <= s1);
    if (run) {
      const u16* RB = FRu + rp*PSTRIDE;
      s16x8 bh_, bl_;
#pragma unroll
      for (int c = 0; c < NXC; ++c) {
        read_b(RB + xc + c*CHUNK, lane, bh_, bl_);
        aR  = MFMA16(Axh[0][c], bh_, aR);  aR  = MFMA16(Axh[0][c], bl_, aR);  aR  = MFMA16(Axl[0][c], bh_, aR);
        aZ  = MFMA16(Axh[1][c], bh_, aZ);  aZ  = MFMA16(Axh[1][c], bl_, aZ);  aZ  = MFMA16(Axl[1][c], bh_, aZ);
        aNi = MFMA16(Axh[2][c], bh_, aNi); aNi = MFMA16(Axh[2][c], bl_, aNi); aNi = MFMA16(Axl[2][c], bh_, aNi);
      }
      read_b(RB + hc, lane, bh_, bl_);
      aR  = MFMA16(Ahh[0], bh_, aR);  aR  = MFMA16(Ahh[0], bl_, aR);  aR  = MFMA16(Ahl[0], bh_, aR);
      aZ  = MFMA16(Ahh[1], bh_, aZ);  aZ  = MFMA16(Ahh[1], bl_, aZ);  aZ  = MFMA16(Ahl[1], bh_, aZ);
      aNh = MFMA16(Ahh[2], bh_, aNh); aNh = MFMA16(Ahh[2], bl_, aNh); aNh = MFMA16(Ahl[2], bh_, aNh);
    }
    __syncthreads();

    if (run)
      combine_write(aR, aZ, aNi, aNh, hprev, FRu + par*PSTRIDE + hc, jbase, nrow, lane);
    if (s >= 5)
      out[((size_t)(b0 + w)*NT + (s-5))*DD + lane] = OST[w*65 + lane];
    if (s <= 510) write_x(FRu, par, w, lane, rx*rm + rl*(1.0f - rm));
    rx = nx; rm = nm; rl = nl;
    __syncthreads();
  }
}

__device__ __forceinline__ void wave_out_fb(
    const float* __restrict__ OW, const float* __restrict__ OBb,
    u16* FRu, float* OST,
    const float* __restrict__ X, const float* __restrict__ Mm, const float* __restrict__ Ll,
    float* __restrict__ out, int b0, int w, int lane)
{
  s16x8 Oh[4], Ol[4];
  f32x4 cO[4];
#pragma unroll
  for (int t4 = 0; t4 < 4; ++t4) {
    load_wfrag(OW, t4*16, 16, 32, 0, lane, Oh[t4], Ol[t4]);
#pragma unroll
    for (int i = 0; i < 4; ++i) cO[t4][i] = OBb[t4*16 + (lane>>4)*4 + i];
  }
  const size_t gbase = ((size_t)(b0 + w))*((size_t)NT*DD) + lane;
  float rx = X[gbase], rm = Mm[gbase], rl = Ll[gbase];
  write_x(FRu, 1, w, lane, rx*rm + rl*(1.0f - rm));
  rx = X[gbase + DD]; rm = Mm[gbase + DD]; rl = Ll[gbase + DD];
  __syncthreads();

  for (int s = 0; s < NSTEP_FB; ++s) {
    const int par = s & 1, rp = par ^ 1;
    float nx = 0.f, nm = 0.f, nl = 0.f;
    if (s <= 509) { size_t g = gbase + (size_t)(s+2)*DD; nx = X[g]; nm = Mm[g]; nl = Ll[g]; }
    if (s >= 5) {
      s16x8 bh_, bl_;
      read_b(FRu + rp*PSTRIDE + H4C, lane, bh_, bl_);
      const int bb = lane & 15, q = lane >> 4;
#pragma unroll
      for (int t4 = 0; t4 < 4; ++t4) {
        f32x4 a_ = cO[t4];
        a_ = MFMA16(Oh[t4], bh_, a_); a_ = MFMA16(Oh[t4], bl_, a_); a_ = MFMA16(Ol[t4], bh_, a_);
        if (bb < 8) {
#pragma unroll
          for (int i = 0; i < 4; ++i) OST[bb*65 + t4*16 + q*4 + i] = a_[i];
        }
      }
    }
    __syncthreads();
    if (s >= 5)
      out[((size_t)(b0 + w)*NT + (s-5))*DD + lane] = OST[w*65 + lane];
    if (s <= 510) write_x(FRu, par, w, lane, rx*rm + rl*(1.0f - rm));
    rx = nx; rm = nm; rl = nl;
    __syncthreads();
  }
}

__global__ __launch_bounds__(NTH, 1)
void gru_mfma(const float* __restrict__ X, const float* __restrict__ M, const float* __restrict__ L,
              const float* __restrict__ wih0, const float* __restrict__ whh0, const float* __restrict__ bih0, const float* __restrict__ bhh0,
              const float* __restrict__ wih1, const float* __restrict__ whh1, const float* __restrict__ bih1, const float* __restrict__ bhh1,
              const float* __restrict__ wih2, const float* __restrict__ whh2, const float* __restrict__ bih2, const float* __restrict__ bhh2,
              const float* __restrict__ wih3, const float* __restrict__ whh3, const float* __restrict__ bih3, const float* __restrict__ bhh3,
              const float* __restrict__ wih4, const float* __restrict__ whh4, const float* __restrict__ bih4, const float* __restrict__ bhh4,
              const float* __restrict__ out_w, const float* __restrict__ out_b,
              float* __restrict__ out)
{
  __shared__ __align__(16) u16 FRu[FRTOT];
  __shared__ float OST[8*65];
  const int tid = threadIdx.x;
  const int w = tid >> 6, lane = tid & 63;
  const int b0 = blockIdx.x * 8;

  for (int i = tid; i < FRTOT; i += NTH) FRu[i] = 0;
  for (int i = tid; i < 8*65; i += NTH) OST[i] = 0.f;
  __syncthreads();

  if (w == 0)
    wave_gru_fb<64,32,2>(wih0,whh0,bih0,bhh0,  0, XIN0, H0C, 0, 511, FRu, OST, X,M,L, out, b0, w, lane);
  else if (w == 1)
    wave_gru_fb<64,32,2>(wih0,whh0,bih0,bhh0, 16, XIN0, H0C, 0, 511, FRu, OST, X,M,L, out, b0, w, lane);
  else if (w == 2)
    wave_gru_fb<32,16,1>(wih1,whh1,bih1,bhh1,  0, H0C,  H1C, 1, 512, FRu, OST, X,M,L, out, b0, w, lane);
  else if (w == 4)
    wave_gru_fb<16, 8,1>(wih2,whh2,bih2,bhh2,  0, H1C,  H2C, 2, 513, FRu, OST, X,M,L, out, b0, w, lane);
  else if (w == 5)
    wave_gru_fb< 8,16,1>(wih3,whh3,bih3,bhh3,  0, H2C,  H3C, 3, 514, FRu, OST, X,M,L, out, b0, w, lane);
  else if (w == 3)
    wave_gru_fb<16,32,1>(wih4,whh4,bih4,bhh4,  0, H3C,  H4C, 4, 515, FRu, OST, X,M,L, out, b0, w, lane);
  else if (w == 6)
    wave_gru_fb<16,32,1>(wih4,whh4,bih4,bhh4, 16, H3C,  H4C, 4, 515, FRu, OST, X,M,L, out, b0, w, lane);
  else
    wave_out_fb(out_w, out_b, FRu, OST, X,M,L, out, b0, w, lane);
}

extern "C" void kernel_launch(void* const* d_in, const int* in_sizes, int n_in,
                              void* d_out, int out_size, void* d_ws, size_t ws_size,
                              hipStream_t stream)
{
  const float* X  = (const float*)d_in[0];
  const float* M  = (const float*)d_in[1];
  const float* L  = (const float*)d_in[2];
  const float* wp[20];
  for (int i = 0; i < 20; ++i) wp[i] = (const float*)d_in[3 + i];
  const float* ow = (const float*)d_in[23];
  const float* ob = (const float*)d_in[24];
  float* out = (float*)d_out;

  const size_t gi_bytes = (size_t)2048 * NT * 96 * sizeof(float);  // 402,653,184
  if (ws_size >= gi_bytes) {
    float* gi = (float*)d_ws;
    gi0_gemm<<<dim3(2048*4), dim3(256), 0, stream>>>(X, M, L, wp[0], wp[2], wp[3], gi);
    gru_rec<<<dim3(256), dim3(NTH), 0, stream>>>(
        gi, wp[1], wp[3],
        wp[4], wp[5], wp[6], wp[7],
        wp[8], wp[9], wp[10], wp[11],
        wp[12], wp[13], wp[14], wp[15],
        wp[16], wp[17], wp[18], wp[19],
        ow, ob, out);
  } else {
    gru_mfma<<<dim3(256), dim3(NTH), 0, stream>>>(
        X, M, L,
        wp[0], wp[1], wp[2], wp[3],
        wp[4], wp[5], wp[6], wp[7],
        wp[8], wp[9], wp[10], wp[11],
        wp[12], wp[13], wp[14], wp[15],
        wp[16], wp[17], wp[18], wp[19],
        ow, ob, out);
  }
}

// Round 11
// 793.591 us; speedup vs baseline: 1.6191x; 1.0855x over previous
//
#include <hip/hip_runtime.h>

typedef short s16x8 __attribute__((ext_vector_type(8)));
typedef short s16x4 __attribute__((ext_vector_type(4)));
typedef float f32x4 __attribute__((ext_vector_type(4)));
typedef unsigned int u32;
typedef unsigned short u16;

#define NT 512
#define DD 64
#define NTH 512

#define CHUNK 1024

// ---------- recurrent kernel LDS (5 h-chunks per parity) ----------
#define P2STRIDE (5*CHUNK)
#define PH0 0
#define PH1 CHUNK
#define PH2 (2*CHUNK)
#define PH3 (3*CHUNK)
#define PH4 (4*CHUNK)
#define FRTOT2 (2*P2STRIDE)   // 10240 u16 = 20 KB
#define NSTEP2 520            // 512 + 8 pipeline stages (mixed deferral)

// ---------- fallback (round-3) LDS ----------
#define PSTRIDE (7*CHUNK)
#define XIN0 0
#define H0C (2*CHUNK)
#define H1C (3*CHUNK)
#define H2C (4*CHUNK)
#define H3C (5*CHUNK)
#define H4C (6*CHUNK)
#define FRTOT (2*PSTRIDE)
#define NSTEP_FB 517

#define MFMA16(A,B,C) __builtin_amdgcn_mfma_f32_16x16x32_bf16(A,B,C,0,0,0)

__device__ __forceinline__ float sigf(float x){ return 1.0f/(1.0f+__expf(-x)); }
__device__ __forceinline__ float tanhf2(float x){ return 2.0f/(1.0f+__expf(-2.0f*x)) - 1.0f; }

__device__ __forceinline__ u16 f2bf(float f) {
  u32 u = __builtin_bit_cast(u32, f);
  return (u16)((u + 0x7fffu + ((u >> 16) & 1u)) >> 16);
}
__device__ __forceinline__ float bf2f(u16 h) {
  u32 u = ((u32)h) << 16;
  return __builtin_bit_cast(float, u);
}

// barrier WITHOUT the vmcnt(0) drain: LDS visibility only (global ops drain at use)
__device__ __forceinline__ void soft_barrier() {
  asm volatile("s_waitcnt lgkmcnt(0)" ::: "memory");
  __builtin_amdgcn_s_barrier();
  asm volatile("" ::: "memory");
}

// wait own LDS writes before own read-back (RAW through LDS within a wave)
__device__ __forceinline__ void lds_fence() {
  asm volatile("s_waitcnt lgkmcnt(0)" ::: "memory");
}

__device__ __forceinline__ u32 cvtpk_bf16(float a, float b) {
  u32 r;
  asm("v_cvt_pk_bf16_f32 %0, %1, %2" : "=v"(r) : "v"(a), "v"(b));
  return r;
}

// xor-8 lane swizzle (within 32-lane half): partner = lane ^ 8
__device__ __forceinline__ float swzf(float v) {
  return __builtin_bit_cast(float,
      __builtin_amdgcn_ds_swizzle(__builtin_bit_cast(int, v), 0x201F));
}

// A-fragment (standard hi/lo pair): lane holds A[row0+(lane&15)][kbase+(lane>>4)*8+e]
__device__ __forceinline__ void load_wfrag(const float* __restrict__ W, int row0, int nrow, int din,
                                           int kbase, int lane, s16x8& hi, s16x8& lo)
{
  const int m = lane & 15, kb = lane >> 4;
#pragma unroll
  for (int e = 0; e < 8; ++e) {
    int k = kbase + kb*8 + e;
    float v = (m < nrow && k < din) ? W[(size_t)(row0 + m)*din + k] : 0.0f;
    u16 h = f2bf(v);
    hi[e] = (short)h;
    lo[e] = (short)f2bf(v - bf2f(h));
  }
}

// Packed A-fragment for real K <= 16: q=0,1 hold hi[k=(q&1)*8+e], q=2,3 hold lo.
__device__ __forceinline__ void load_wfrag_pk(const float* __restrict__ W, int row0, int nrow,
                                              int stride, int KR, int lane, s16x8& A1)
{
  const int m = lane & 15, q = lane >> 4;
  const bool lohalf = q >= 2;
  const int kb = (q & 1) * 8;
#pragma unroll
  for (int e = 0; e < 8; ++e) {
    int k = kb + e;
    float v = (m < nrow && k < KR) ? W[(size_t)(row0 + m)*stride + k] : 0.0f;
    u16 h = f2bf(v);
    A1[e] = (short)(lohalf ? f2bf(v - bf2f(h)) : h);
  }
}

// B-fragment read (standard): hi at +0, lo at +128 within each 256-u16 k-block
__device__ __forceinline__ void read_b(const u16* base, int lane, s16x8& hi, s16x8& lo)
{
  const int off = ((lane >> 4) << 8) + ((lane & 15) << 3);
  hi = *(const s16x8*)(base + off);
  lo = *(const s16x8*)(base + off + 128);
}

// Packed B read for real K <= 16: b1 = [hi|lo], b2 = halves crossed (addr ^ 128).
__device__ __forceinline__ void read_b_pk(const u16* base, int lane, s16x8& b1, s16x8& b2)
{
  const int q = lane >> 4;
  const int off1 = ((q & 1) << 8) + ((q >> 1) << 7) + ((lane & 15) << 3);
  b1 = *(const s16x8*)(base + off1);
  b2 = *(const s16x8*)(base + (off1 ^ 128));
}

// Lane-split combine: lanes bb<8 take j-pair {q*4,q*4+1}, lanes bb>=8 take
// {q*4+2,q*4+3} of batch bb-8 via xor-8 swizzle (phantom cols repurposed).
// Halves exp/rcp count. All 64 lanes write (128 h-values = 16 j x 8 bb).
template<bool NI_OWN>
__device__ __forceinline__ void combine_split8(
    f32x4 aR, f32x4 aZ, f32x4 aNi, f32x4 aNh,
    float (&hp)[2], u16* dstC, int jbase, int nrow, int lane)
{
  const int bb = lane & 15, q = lane >> 4;
  const bool hih = (bb & 8) != 0;
  float sR2 = swzf(aR[2]),  sR3 = swzf(aR[3]);
  float sZ2 = swzf(aZ[2]),  sZ3 = swzf(aZ[3]);
  float sH2 = swzf(aNh[2]), sH3 = swzf(aNh[3]);
  float r0  = hih ? sR2 : aR[0],  r1  = hih ? sR3 : aR[1];
  float z0  = hih ? sZ2 : aZ[0],  z1  = hih ? sZ3 : aZ[1];
  float nh0 = hih ? sH2 : aNh[0], nh1 = hih ? sH3 : aNh[1];
  float ni0, ni1;
  if constexpr (NI_OWN) {          // aNi duplicated across lane / lane^8 (gi regs)
    ni0 = hih ? aNi[2] : aNi[0];
    ni1 = hih ? aNi[3] : aNi[1];
  } else {
    float sN2 = swzf(aNi[2]), sN3 = swzf(aNi[3]);
    ni0 = hih ? sN2 : aNi[0];
    ni1 = hih ? sN3 : aNi[1];
  }
  float rr0 = sigf(r0), rr1 = sigf(r1);
  float zz0 = sigf(z0), zz1 = sigf(z1);
  float n0 = tanhf2(ni0 + rr0*nh0), n1 = tanhf2(ni1 + rr1*nh1);
  float h0 = (1.0f - zz0)*n0 + zz0*hp[0];
  float h1 = (1.0f - zz1)*n1 + zz1*hp[1];
  hp[0] = h0; hp[1] = h1;
  const int jj = q*4 + (hih ? 2 : 0);
  if (jj < nrow) {
    const int j = jbase + jj;
    u32 ph = cvtpk_bf16(h0, h1);
    float f0 = h0 - __builtin_bit_cast(float, ph << 16);
    float f1 = h1 - __builtin_bit_cast(float, ph & 0xffff0000u);
    u32 pl = cvtpk_bf16(f0, f1);
    u16* dst = dstC + ((j >> 3) << 8) + ((bb & 7) << 3) + (j & 7);
    *(u32*)dst = ph;
    *(u32*)(dst + 128) = pl;
  }
}

// =====================================================================
// Phase 1: gi0[b][t][96] = Wih0 @ x_imp(b,t) + bih0 (+bhh0 for r,z rows)
// =====================================================================
__global__ __launch_bounds__(256)
void gi0_gemm(const float* __restrict__ X, const float* __restrict__ M, const float* __restrict__ L,
              const float* __restrict__ wih0, const float* __restrict__ bih0,
              const float* __restrict__ bhh0,
              float* __restrict__ gi)
{
  __shared__ u32 xs[128*65];
  const int tid = threadIdx.x;
  const int wv = tid >> 6, lane = tid & 63;
  const int q = lane >> 4;
  const int b = blockIdx.x >> 2;
  const int t0 = (blockIdx.x & 3) * 128;
  const size_t base = ((size_t)b*NT + t0)*DD;

  for (int i = tid; i < 128*64; i += 256) {
    float x = X[base+i], m = M[base+i], l = L[base+i];
    float v = x*m + l*(1.0f - m);
    u16 h = f2bf(v);
    u16 lo2 = f2bf(v - bf2f(h));
    const int t = i >> 6, d = i & 63;
    xs[t*65 + d] = (u32)h | ((u32)lo2 << 16);
  }

  s16x8 Ah[6][2], Al[6][2];
  f32x4 cb[6];
#pragma unroll
  for (int tile = 0; tile < 6; ++tile) {
#pragma unroll
    for (int c = 0; c < 2; ++c)
      load_wfrag(wih0, tile*16, 16, 64, c*32, lane, Ah[tile][c], Al[tile][c]);
#pragma unroll
    for (int i = 0; i < 4; ++i) {
      int row = tile*16 + q*4 + i;
      float bv = bih0[row];
      if (tile < 4) bv += bhh0[row];
      cb[tile][i] = bv;
    }
  }
  __syncthreads();

#pragma unroll
  for (int g2 = 0; g2 < 2; ++g2) {
    const int tloc = g2*64 + wv*16 + (lane & 15);
    s16x8 Bh[2], Bl[2];
#pragma unroll
    for (int c = 0; c < 2; ++c) {
      const u32* p = &xs[tloc*65 + c*32 + q*8];
#pragma unroll
      for (int e = 0; e < 8; ++e) {
        u32 v = p[e];
        Bh[c][e] = (short)(v & 0xffffu);
        Bl[c][e] = (short)(v >> 16);
      }
    }
    float* gp = gi + ((size_t)b*NT + t0 + tloc)*96 + q*4;
#pragma unroll
    for (int tile = 0; tile < 6; ++tile) {
      f32x4 acc = cb[tile];
#pragma unroll
      for (int c = 0; c < 2; ++c) {
        acc = MFMA16(Ah[tile][c], Bh[c], acc);
        acc = MFMA16(Ah[tile][c], Bl[c], acc);
        acc = MFMA16(Al[tile][c], Bh[c], acc);
      }
      *(f32x4*)(gp + tile*16) = acc;
    }
  }
}

// =====================================================================
// Phase 2: mixed-schedule recurrent kernel.
//  - L0 (w0/w1, j-split) and L4 (w3/w6, j-split): NON-deferred (R9 order) —
//    cross-wave h halves must be one barrier old. Split combine kept.
//  - L1/L2/L3 (single-wave): deferred combine (same-step own-wave readback).
//  Offsets: h0(t)@t, h1(t)@t+2, h2(t)@t+4, h3(t)@t+6, h4(t)@t+7, OUT@t+8.
// =====================================================================
__device__ __forceinline__ void wave_l0(
    const float* __restrict__ Whh, const float* __restrict__ bhh,
    const float* __restrict__ gi, int jbase,
    u16* FRu, int b0, int lane)
{
  s16x8 Ahh[3], Ahl[3];
#pragma unroll
  for (int g = 0; g < 3; ++g)
    load_wfrag(Whh, g*32 + jbase, 16, 32, 0, lane, Ahh[g], Ahl[g]);
  const int q = lane >> 4;
  f32x4 cNh;
#pragma unroll
  for (int i = 0; i < 4; ++i) cNh[i] = bhh[64 + jbase + q*4 + i];
  float hp[2] = {0.f, 0.f};

  const float* gb = gi + (size_t)(b0 + (lane & 7)) * ((size_t)NT*96) + jbase + q*4;
  f32x4 AR, AZ, AN, BR, BZ, BN;
  AR = *(const f32x4*)(gb);      AZ = *(const f32x4*)(gb+32);  AN = *(const f32x4*)(gb+64);
  BR = *(const f32x4*)(gb+96);   BZ = *(const f32x4*)(gb+128); BN = *(const f32x4*)(gb+160);

  auto body = [&](int st, const u16* R, u16* Wp, f32x4& gR, f32x4& gZ, f32x4& gN) {
    if (st < NT) {
      f32x4 aR = gR, aZ = gZ, aNi = gN, aNh = cNh;   // biases pre-folded in gi
      s16x8 bh_, bl_;
      read_b(R + PH0, lane, bh_, bl_);   // h0(t-1): written LAST step (race-free)
      aR  = MFMA16(Ahh[0], bh_, aR);  aR  = MFMA16(Ahh[0], bl_, aR);  aR  = MFMA16(Ahl[0], bh_, aR);
      aZ  = MFMA16(Ahh[1], bh_, aZ);  aZ  = MFMA16(Ahh[1], bl_, aZ);  aZ  = MFMA16(Ahl[1], bh_, aZ);
      aNh = MFMA16(Ahh[2], bh_, aNh); aNh = MFMA16(Ahh[2], bl_, aNh); aNh = MFMA16(Ahl[2], bh_, aNh);
      combine_split8<true>(aR, aZ, aNi, aNh, hp, Wp + PH0, jbase, 16, lane);
    }
    if (st + 2 < NT) {
      const float* p = gb + (size_t)(st + 2)*96;
      gR = *(const f32x4*)(p); gZ = *(const f32x4*)(p+32); gN = *(const f32x4*)(p+64);
    }
  };

  for (int s = 0; s < NSTEP2; s += 2) {
    body(s,     FRu + P2STRIDE, FRu,            AR, AZ, AN);  // rp=1, par=0
    soft_barrier();
    body(s + 1, FRu,            FRu + P2STRIDE, BR, BZ, BN);  // rp=0, par=1
    soft_barrier();
  }
}

// NON-deferred mid wave (used for j-split L4): reads x and own h(t-1) from rp.
template<int DIN, int DH, bool PKX, bool PKH>
__device__ __forceinline__ void wave_mid_nd(
    const float* __restrict__ Wih, const float* __restrict__ Whh,
    const float* __restrict__ bih, const float* __restrict__ bhh,
    int jbase, int xc, int hc, int s0, int s1,
    u16* FRu, int lane)
{
  const int nrow = (DH - jbase) < 16 ? (DH - jbase) : 16;
  s16x8 Ax1[3], Axh[3], Axl[3], Ah1[3], Ahh[3], Ahl[3];
#pragma unroll
  for (int g = 0; g < 3; ++g) {
    if constexpr (PKX) load_wfrag_pk(Wih, g*DH + jbase, nrow, DIN, DIN, lane, Ax1[g]);
    else               load_wfrag(Wih, g*DH + jbase, nrow, DIN, 0, lane, Axh[g], Axl[g]);
    if constexpr (PKH) load_wfrag_pk(Whh, g*DH + jbase, nrow, DH, DH, lane, Ah1[g]);
    else               load_wfrag(Whh, g*DH + jbase, nrow, DH, 0, lane, Ahh[g], Ahl[g]);
  }
  const int q = lane >> 4;
  f32x4 cR, cZ, cNi, cNh;
#pragma unroll
  for (int i = 0; i < 4; ++i) {
    int lr = q*4 + i;
    int j = jbase + lr;
    bool jr = lr < nrow;
    cR[i]  = jr ? bih[j] + bhh[j] : 0.f;
    cZ[i]  = jr ? bih[DH+j] + bhh[DH+j] : 0.f;
    cNi[i] = jr ? bih[2*DH+j] : 0.f;
    cNh[i] = jr ? bhh[2*DH+j] : 0.f;
  }
  float hp[2] = {0.f, 0.f};

  auto body = [&](int st, const u16* R, u16* Wp) {
    if (st >= s0 && st <= s1) {
      f32x4 aR = cR, aZ = cZ, aNi = cNi, aNh = cNh;
      if constexpr (PKX) {
        s16x8 b1, b2;
        read_b_pk(R + xc, lane, b1, b2);
        aR  = MFMA16(Ax1[0], b1, aR);  aR  = MFMA16(Ax1[0], b2, aR);
        aZ  = MFMA16(Ax1[1], b1, aZ);  aZ  = MFMA16(Ax1[1], b2, aZ);
        aNi = MFMA16(Ax1[2], b1, aNi); aNi = MFMA16(Ax1[2], b2, aNi);
      } else {
        s16x8 bh_, bl_;
        read_b(R + xc, lane, bh_, bl_);
        aR  = MFMA16(Axh[0], bh_, aR);  aR  = MFMA16(Axh[0], bl_, aR);  aR  = MFMA16(Axl[0], bh_, aR);
        aZ  = MFMA16(Axh[1], bh_, aZ);  aZ  = MFMA16(Axh[1], bl_, aZ);  aZ  = MFMA16(Axl[1], bh_, aZ);
        aNi = MFMA16(Axh[2], bh_, aNi); aNi = MFMA16(Axh[2], bl_, aNi); aNi = MFMA16(Axl[2], bh_, aNi);
      }
      if constexpr (PKH) {
        s16x8 b1, b2;
        read_b_pk(R + hc, lane, b1, b2);   // h(t-1): written LAST step (race-free)
        aR  = MFMA16(Ah1[0], b1, aR);  aR  = MFMA16(Ah1[0], b2, aR);
        aZ  = MFMA16(Ah1[1], b1, aZ);  aZ  = MFMA16(Ah1[1], b2, aZ);
        aNh = MFMA16(Ah1[2], b1, aNh); aNh = MFMA16(Ah1[2], b2, aNh);
      } else {
        s16x8 bh_, bl_;
        read_b(R + hc, lane, bh_, bl_);
        aR  = MFMA16(Ahh[0], bh_, aR);  aR  = MFMA16(Ahh[0], bl_, aR);  aR  = MFMA16(Ahl[0], bh_, aR);
        aZ  = MFMA16(Ahh[1], bh_, aZ);  aZ  = MFMA16(Ahh[1], bl_, aZ);  aZ  = MFMA16(Ahl[1], bh_, aZ);
        aNh = MFMA16(Ahh[2], bh_, aNh); aNh = MFMA16(Ahh[2], bl_, aNh); aNh = MFMA16(Ahl[2], bh_, aNh);
      }
      combine_split8<false>(aR, aZ, aNi, aNh, hp, Wp + hc, jbase, nrow, lane);
    }
  };

  for (int s = 0; s < NSTEP2; s += 2) {
    body(s,     FRu + P2STRIDE, FRu);            // rp=1, par=0
    soft_barrier();
    body(s + 1, FRu,            FRu + P2STRIDE); // rp=0, par=1
    soft_barrier();
  }
}

// DEFERRED mid wave (single-wave layers only): combine(t-1) this step, then
// own-wave readback of just-written h(t-1) (same-wave DS in-order).
template<int DIN, int DH, bool PKX, bool PKH>
__device__ __forceinline__ void wave_mid_df(
    const float* __restrict__ Wih, const float* __restrict__ Whh,
    const float* __restrict__ bih, const float* __restrict__ bhh,
    int jbase, int xc, int hc, int s0,
    u16* FRu, int lane)
{
  const int nrow = (DH - jbase) < 16 ? (DH - jbase) : 16;
  s16x8 Ax1[3], Axh[3], Axl[3], Ah1[3], Ahh[3], Ahl[3];
#pragma unroll
  for (int g = 0; g < 3; ++g) {
    if constexpr (PKX) load_wfrag_pk(Wih, g*DH + jbase, nrow, DIN, DIN, lane, Ax1[g]);
    else               load_wfrag(Wih, g*DH + jbase, nrow, DIN, 0, lane, Axh[g], Axl[g]);
    if constexpr (PKH) load_wfrag_pk(Whh, g*DH + jbase, nrow, DH, DH, lane, Ah1[g]);
    else               load_wfrag(Whh, g*DH + jbase, nrow, DH, 0, lane, Ahh[g], Ahl[g]);
  }
  const int q = lane >> 4;
  f32x4 cR, cZ, cNi, cNh;
#pragma unroll
  for (int i = 0; i < 4; ++i) {
    int lr = q*4 + i;
    int j = jbase + lr;
    bool jr = lr < nrow;
    cR[i]  = jr ? bih[j] + bhh[j] : 0.f;
    cZ[i]  = jr ? bih[DH+j] + bhh[DH+j] : 0.f;
    cNi[i] = jr ? bih[2*DH+j] : 0.f;
    cNh[i] = jr ? bhh[2*DH+j] : 0.f;
  }
  f32x4 accR = {}, accZ = {}, accNi = {}, accNh = {};
  float hp[2] = {0.f, 0.f};

  auto body = [&](int st, const u16* R, u16* Wp) {
    const bool compute = (st >= s0) && (st <= s0 + 511);
    const bool docomb  = (st >= s0 + 1) && (st <= s0 + 512);
    f32x4 nR, nZ, nNi, nNh;
    if (compute) {
      nR = cR; nZ = cZ; nNi = cNi; nNh = cNh;
      if constexpr (PKX) {
        s16x8 b1, b2;
        read_b_pk(R + xc, lane, b1, b2);
        nR  = MFMA16(Ax1[0], b1, nR);  nR  = MFMA16(Ax1[0], b2, nR);
        nZ  = MFMA16(Ax1[1], b1, nZ);  nZ  = MFMA16(Ax1[1], b2, nZ);
        nNi = MFMA16(Ax1[2], b1, nNi); nNi = MFMA16(Ax1[2], b2, nNi);
      } else {
        s16x8 bh_, bl_;
        read_b(R + xc, lane, bh_, bl_);
        nR  = MFMA16(Axh[0], bh_, nR);  nR  = MFMA16(Axh[0], bl_, nR);  nR  = MFMA16(Axl[0], bh_, nR);
        nZ  = MFMA16(Axh[1], bh_, nZ);  nZ  = MFMA16(Axh[1], bl_, nZ);  nZ  = MFMA16(Axl[1], bh_, nZ);
        nNi = MFMA16(Axh[2], bh_, nNi); nNi = MFMA16(Axh[2], bl_, nNi); nNi = MFMA16(Axl[2], bh_, nNi);
      }
    }
    if (docomb) {
      combine_split8<false>(accR, accZ, accNi, accNh, hp, Wp + hc, jbase, nrow, lane);
      lds_fence();
    }
    if (compute) {
      if constexpr (PKH) {
        s16x8 b1, b2;
        read_b_pk(Wp + hc, lane, b1, b2);   // own just-written h(t-1)
        nR  = MFMA16(Ah1[0], b1, nR);  nR  = MFMA16(Ah1[0], b2, nR);
        nZ  = MFMA16(Ah1[1], b1, nZ);  nZ  = MFMA16(Ah1[1], b2, nZ);
        nNh = MFMA16(Ah1[2], b1, nNh); nNh = MFMA16(Ah1[2], b2, nNh);
      } else {
        s16x8 bh_, bl_;
        read_b(Wp + hc, lane, bh_, bl_);
        nR  = MFMA16(Ahh[0], bh_, nR);  nR  = MFMA16(Ahh[0], bl_, nR);  nR  = MFMA16(Ahl[0], bh_, nR);
        nZ  = MFMA16(Ahh[1], bh_, nZ);  nZ  = MFMA16(Ahh[1], bl_, nZ);  nZ  = MFMA16(Ahl[1], bh_, nZ);
        nNh = MFMA16(Ahh[2], bh_, nNh); nNh = MFMA16(Ahh[2], bl_, nNh); nNh = MFMA16(Ahl[2], bh_, nNh);
      }
      accR = nR; accZ = nZ; accNi = nNi; accNh = nNh;
    }
  };

  for (int s = 0; s < NSTEP2; s += 2) {
    body(s,     FRu + P2STRIDE, FRu);            // rp=1, par=0
    soft_barrier();
    body(s + 1, FRu,            FRu + P2STRIDE); // rp=0, par=1
    soft_barrier();
  }
}

__device__ __forceinline__ void wave_out2(
    const float* __restrict__ OW, const float* __restrict__ OBb,
    u16* FRu, float* __restrict__ out, int b0, int lane)
{
  s16x8 Oh[4], Ol[4];
  f32x4 cO[4];
  const int q = lane >> 4, bb = lane & 15;
#pragma unroll
  for (int t4 = 0; t4 < 4; ++t4) {
    load_wfrag(OW, t4*16, 16, 32, 0, lane, Oh[t4], Ol[t4]);
#pragma unroll
    for (int i = 0; i < 4; ++i) cO[t4][i] = OBb[t4*16 + q*4 + i];
  }
  float* ob = out + ((size_t)(b0 + (bb & 7))*NT)*DD + q*4;

  auto emit = [&](int st, const u16* R) {
    if (st >= 8 && st <= 519) {   // h4(t), t = st-8, written at step st-1
      s16x8 bh_, bl_;
      read_b(R + PH4, lane, bh_, bl_);
#pragma unroll
      for (int t4 = 0; t4 < 4; ++t4) {
        f32x4 a_ = cO[t4];
        a_ = MFMA16(Oh[t4], bh_, a_); a_ = MFMA16(Oh[t4], bl_, a_); a_ = MFMA16(Ol[t4], bh_, a_);
        if (bb < 8) *(f32x4*)(ob + t4*16) = a_;   // direct C-frag store
      }
      ob += DD;
    }
  };

  for (int s = 0; s < NSTEP2; s += 2) {
    emit(s,     FRu + P2STRIDE);   // rp=1
    soft_barrier();
    emit(s + 1, FRu);              // rp=0
    soft_barrier();
  }
}

__global__ __launch_bounds__(NTH, 1)
void gru_rec(const float* __restrict__ gi,
             const float* __restrict__ whh0, const float* __restrict__ bhh0,
             const float* __restrict__ wih1, const float* __restrict__ whh1, const float* __restrict__ bih1, const float* __restrict__ bhh1,
             const float* __restrict__ wih2, const float* __restrict__ whh2, const float* __restrict__ bih2, const float* __restrict__ bhh2,
             const float* __restrict__ wih3, const float* __restrict__ whh3, const float* __restrict__ bih3, const float* __restrict__ bhh3,
             const float* __restrict__ wih4, const float* __restrict__ whh4, const float* __restrict__ bih4, const float* __restrict__ bhh4,
             const float* __restrict__ out_w, const float* __restrict__ out_b,
             float* __restrict__ out)
{
  __shared__ __align__(16) u16 FRu[FRTOT2];
  const int tid = threadIdx.x;
  const int w = tid >> 6, lane = tid & 63;
  const int b0 = blockIdx.x * 8;

  for (int i = tid; i < FRTOT2; i += NTH) FRu[i] = 0;
  __syncthreads();

  if (w == 0)
    wave_l0(whh0, bhh0, gi,  0, FRu, b0, lane);                                 // h0(t)@t
  else if (w == 1)
    wave_l0(whh0, bhh0, gi, 16, FRu, b0, lane);
  else if (w == 2)
    wave_mid_df<32,16,false,true >(wih1,whh1,bih1,bhh1,  0, PH0, PH1, 1, FRu, lane);  // h1(t)@t+2
  else if (w == 4)
    wave_mid_df<16, 8,true ,true >(wih2,whh2,bih2,bhh2,  0, PH1, PH2, 3, FRu, lane);  // h2(t)@t+4
  else if (w == 5)
    wave_mid_df< 8,16,true ,true >(wih3,whh3,bih3,bhh3,  0, PH2, PH3, 5, FRu, lane);  // h3(t)@t+6
  else if (w == 3)
    wave_mid_nd<16,32,true ,false>(wih4,whh4,bih4,bhh4,  0, PH3, PH4, 7, 518, FRu, lane);  // h4(t)@t+7
  else if (w == 6)
    wave_mid_nd<16,32,true ,false>(wih4,whh4,bih4,bhh4, 16, PH3, PH4, 7, 518, FRu, lane);
  else
    wave_out2(out_w, out_b, FRu, out, b0, lane);                                 // out(t)@t+8
}

// =====================================================================
// Fallback: round-3 kernel (used only if ws_size is too small for gi0)
// =====================================================================
__device__ __forceinline__ void combine_write(
    f32x4 aR, f32x4 aZ, f32x4 aNi, f32x4 aNh,
    float (&hprev)[4], u16* hdst_base, int jbase, int nrow, int lane)
{
  const int bb = lane & 15, q = lane >> 4;
  float hv[4];
#pragma unroll
  for (int i = 0; i < 4; ++i) {
    float rr = sigf(aR[i]);
    float zz = sigf(aZ[i]);
    float nn = tanhf2(aNi[i] + rr*aNh[i]);
    hv[i] = (1.0f - zz)*nn + zz*hprev[i];
    hprev[i] = hv[i];
  }
  if (bb < 8 && q*4 < nrow) {
    const int j = jbase + q*4;
    const int kb = j >> 3, e = j & 7;
    s16x4 hh, ll;
#pragma unroll
    for (int i = 0; i < 4; ++i) {
      u16 h = f2bf(hv[i]);
      hh[i] = (short)h;
      ll[i] = (short)f2bf(hv[i] - bf2f(h));
    }
    u16* dst = hdst_base + kb*256 + bb*8 + e;
    *(s16x4*)dst = hh;
    *(s16x4*)(dst + 128) = ll;
  }
}

__device__ __forceinline__ void write_x(u16* FRu, int par, int w, int lane, float v)
{
  const int d = lane;
  const int chunk = d >> 5, kb = (d >> 3) & 3, e = d & 7;
  u16 h = f2bf(v);
  u16 l2 = f2bf(v - bf2f(h));
  u16* p = FRu + par*PSTRIDE + XIN0 + chunk*CHUNK + kb*256 + w*8 + e;
  p[0] = h; p[128] = l2;
}

template<int DIN, int DH, int NXC>
__device__ __forceinline__ void wave_gru_fb(
    const float* __restrict__ Wih, const float* __restrict__ Whh,
    const float* __restrict__ bih, const float* __restrict__ bhh,
    int jbase, int xc, int hc, int s0, int s1,
    u16* FRu, float* OST,
    const float* __restrict__ X, const float* __restrict__ Mm, const float* __restrict__ Ll,
    float* __restrict__ out, int b0, int w, int lane)
{
  const int nrow = (DH - jbase) < 16 ? (DH - jbase) : 16;
  s16x8 Axh[3][NXC], Axl[3][NXC], Ahh[3], Ahl[3];
#pragma unroll
  for (int g = 0; g < 3; ++g) {
#pragma unroll
    for (int c = 0; c < NXC; ++c)
      load_wfrag(Wih, g*DH + jbase, nrow, DIN, c*32, lane, Axh[g][c], Axl[g][c]);
    load_wfrag(Whh, g*DH + jbase, nrow, DH, 0, lane, Ahh[g], Ahl[g]);
  }
  f32x4 cR, cZ, cNi, cNh;
  {
    const int q = lane >> 4;
#pragma unroll
    for (int i = 0; i < 4; ++i) {
      int lr = q*4 + i;
      int j = jbase + lr;
      bool jr = lr < nrow;
      cR[i]  = jr ? bih[j] + bhh[j] : 0.f;
      cZ[i]  = jr ? bih[DH+j] + bhh[DH+j] : 0.f;
      cNi[i] = jr ? bih[2*DH+j] : 0.f;
      cNh[i] = jr ? bhh[2*DH+j] : 0.f;
    }
  }
  float hprev[4] = {0.f, 0.f, 0.f, 0.f};

  const size_t gbase = ((size_t)(b0 + w))*((size_t)NT*DD) + lane;
  float rx = X[gbase], rm = Mm[gbase], rl = Ll[gbase];
  write_x(FRu, 1, w, lane, rx*rm + rl*(1.0f - rm));
  rx = X[gbase + DD]; rm = Mm[gbase + DD]; rl = Ll[gbase + DD];
  __syncthreads();

  for (int s = 0; s < NSTEP_FB; ++s) {
    const int par = s & 1, rp = par ^ 1;
    float nx = 0.f, nm = 0.f, nl = 0.f;
    if (s <= 509) {
      size_t g = gbase + (size_t)(s+2)*DD;
      nx = X[g]; nm = Mm[g]; nl = Ll[g];
    }
    f32x4 aR = cR, aZ = cZ, aNi = cNi, aNh = cNh;
    const bool run = (s >= s0) && (s <= s1);
    if (run) {
      const u16* RB = FRu + rp*PSTRIDE;
      s16x8 bh_, bl_;
#pragma unroll
      for (int c = 0; c < NXC; ++c) {
        read_b(RB + xc + c*CHUNK, lane, bh_, bl_);
        aR  = MFMA16(Axh[0][c], bh_, aR);  aR  = MFMA16(Axh[0][c], bl_, aR);  aR  = MFMA16(Axl[0][c], bh_, aR);
        aZ  = MFMA16(Axh[1][c], bh_, aZ);  aZ  = MFMA16(Axh[1][c], bl_, aZ);  aZ  = MFMA16(Axl[1][c], bh_, aZ);
        aNi = MFMA16(Axh[2][c], bh_, aNi); aNi = MFMA16(Axh[2][c], bl_, aNi); aNi = MFMA16(Axl[2][c], bh_, aNi);
      }
      read_b(RB + hc, lane, bh_, bl_);
      aR  = MFMA16(Ahh[0], bh_, aR);  aR  = MFMA16(Ahh[0], bl_, aR);  aR  = MFMA16(Ahl[0], bh_, aR);
      aZ  = MFMA16(Ahh[1], bh_, aZ);  aZ  = MFMA16(Ahh[1], bl_, aZ);  aZ  = MFMA16(Ahl[1], bh_, aZ);
      aNh = MFMA16(Ahh[2], bh_, aNh); aNh = MFMA16(Ahh[2], bl_, aNh); aNh = MFMA16(Ahl[2], bh_, aNh);
    }
    __syncthreads();

    if (run)
      combine_write(aR, aZ, aNi, aNh, hprev, FRu + par*PSTRIDE + hc, jbase, nrow, lane);
    if (s >= 5)
      out[((size_t)(b0 + w)*NT + (s-5))*DD + lane] = OST[w*65 + lane];
    if (s <= 510) write_x(FRu, par, w, lane, rx*rm + rl*(1.0f - rm));
    rx = nx; rm = nm; rl = nl;
    __syncthreads();
  }
}

__device__ __forceinline__ void wave_out_fb(
    const float* __restrict__ OW, const float* __restrict__ OBb,
    u16* FRu, float* OST,
    const float* __restrict__ X, const float* __restrict__ Mm, const float* __restrict__ Ll,
    float* __restrict__ out, int b0, int w, int lane)
{
  s16x8 Oh[4], Ol[4];
  f32x4 cO[4];
#pragma unroll
  for (int t4 = 0; t4 < 4; ++t4) {
    load_wfrag(OW, t4*16, 16, 32, 0, lane, Oh[t4], Ol[t4]);
#pragma unroll
    for (int i = 0; i < 4; ++i) cO[t4][i] = OBb[t4*16 + (lane>>4)*4 + i];
  }
  const size_t gbase = ((size_t)(b0 + w))*((size_t)NT*DD) + lane;
  float rx = X[gbase], rm = Mm[gbase], rl = Ll[gbase];
  write_x(FRu, 1, w, lane, rx*rm + rl*(1.0f - rm));
  rx = X[gbase + DD]; rm = Mm[gbase + DD]; rl = Ll[gbase + DD];
  __syncthreads();

  for (int s = 0; s < NSTEP_FB; ++s) {
    const int par = s & 1, rp = par ^ 1;
    float nx = 0.f, nm = 0.f, nl = 0.f;
    if (s <= 509) { size_t g = gbase + (size_t)(s+2)*DD; nx = X[g]; nm = Mm[g]; nl = Ll[g]; }
    if (s >= 5) {
      s16x8 bh_, bl_;
      read_b(FRu + rp*PSTRIDE + H4C, lane, bh_, bl_);
      const int bb = lane & 15, q = lane >> 4;
#pragma unroll
      for (int t4 = 0; t4 < 4; ++t4) {
        f32x4 a_ = cO[t4];
        a_ = MFMA16(Oh[t4], bh_, a_); a_ = MFMA16(Oh[t4], bl_, a_); a_ = MFMA16(Ol[t4], bh_, a_);
        if (bb < 8) {
#pragma unroll
          for (int i = 0; i < 4; ++i) OST[bb*65 + t4*16 + q*4 + i] = a_[i];
        }
      }
    }
    __syncthreads();
    if (s >= 5)
      out[((size_t)(b0 + w)*NT + (s-5))*DD + lane] = OST[w*65 + lane];
    if (s <= 510) write_x(FRu, par, w, lane, rx*rm + rl*(1.0f - rm));
    rx = nx; rm = nm; rl = nl;
    __syncthreads();
  }
}

__global__ __launch_bounds__(NTH, 1)
void gru_mfma(const float* __restrict__ X, const float* __restrict__ M, const float* __restrict__ L,
              const float* __restrict__ wih0, const float* __restrict__ whh0, const float* __restrict__ bih0, const float* __restrict__ bhh0,
              const float* __restrict__ wih1, const float* __restrict__ whh1, const float* __restrict__ bih1, const float* __restrict__ bhh1,
              const float* __restrict__ wih2, const float* __restrict__ whh2, const float* __restrict__ bih2, const float* __restrict__ bhh2,
              const float* __restrict__ wih3, const float* __restrict__ whh3, const float* __restrict__ bih3, const float* __restrict__ bhh3,
              const float* __restrict__ wih4, const float* __restrict__ whh4, const float* __restrict__ bih4, const float* __restrict__ bhh4,
              const float* __restrict__ out_w, const float* __restrict__ out_b,
              float* __restrict__ out)
{
  __shared__ __align__(16) u16 FRu[FRTOT];
  __shared__ float OST[8*65];
  const int tid = threadIdx.x;
  const int w = tid >> 6, lane = tid & 63;
  const int b0 = blockIdx.x * 8;

  for (int i = tid; i < FRTOT; i += NTH) FRu[i] = 0;
  for (int i = tid; i < 8*65; i += NTH) OST[i] = 0.f;
  __syncthreads();

  if (w == 0)
    wave_gru_fb<64,32,2>(wih0,whh0,bih0,bhh0,  0, XIN0, H0C, 0, 511, FRu, OST, X,M,L, out, b0, w, lane);
  else if (w == 1)
    wave_gru_fb<64,32,2>(wih0,whh0,bih0,bhh0, 16, XIN0, H0C, 0, 511, FRu, OST, X,M,L, out, b0, w, lane);
  else if (w == 2)
    wave_gru_fb<32,16,1>(wih1,whh1,bih1,bhh1,  0, H0C,  H1C, 1, 512, FRu, OST, X,M,L, out, b0, w, lane);
  else if (w == 4)
    wave_gru_fb<16, 8,1>(wih2,whh2,bih2,bhh2,  0, H1C,  H2C, 2, 513, FRu, OST, X,M,L, out, b0, w, lane);
  else if (w == 5)
    wave_gru_fb< 8,16,1>(wih3,whh3,bih3,bhh3,  0, H2C,  H3C, 3, 514, FRu, OST, X,M,L, out, b0, w, lane);
  else if (w == 3)
    wave_gru_fb<16,32,1>(wih4,whh4,bih4,bhh4,  0, H3C,  H4C, 4, 515, FRu, OST, X,M,L, out, b0, w, lane);
  else if (w == 6)
    wave_gru_fb<16,32,1>(wih4,whh4,bih4,bhh4, 16, H3C,  H4C, 4, 515, FRu, OST, X,M,L, out, b0, w, lane);
  else
    wave_out_fb(out_w, out_b, FRu, OST, X,M,L, out, b0, w, lane);
}

extern "C" void kernel_launch(void* const* d_in, const int* in_sizes, int n_in,
                              void* d_out, int out_size, void* d_ws, size_t ws_size,
                              hipStream_t stream)
{
  const float* X  = (const float*)d_in[0];
  const float* M  = (const float*)d_in[1];
  const float* L  = (const float*)d_in[2];
  const float* wp[20];
  for (int i = 0; i < 20; ++i) wp[i] = (const float*)d_in[3 + i];
  const float* ow = (const float*)d_in[23];
  const float* ob = (const float*)d_in[24];
  float* out = (float*)d_out;

  const size_t gi_bytes = (size_t)2048 * NT * 96 * sizeof(float);  // 402,653,184
  if (ws_size >= gi_bytes) {
    float* gi = (float*)d_ws;
    gi0_gemm<<<dim3(2048*4), dim3(256), 0, stream>>>(X, M, L, wp[0], wp[2], wp[3], gi);
    gru_rec<<<dim3(256), dim3(NTH), 0, stream>>>(
        gi, wp[1], wp[3],
        wp[4], wp[5], wp[6], wp[7],
        wp[8], wp[9], wp[10], wp[11],
        wp[12], wp[13], wp[14], wp[15],
        wp[16], wp[17], wp[18], wp[19],
        ow, ob, out);
  } else {
    gru_mfma<<<dim3(256), dim3(NTH), 0, stream>>>(
        X, M, L,
        wp[0], wp[1], wp[2], wp[3],
        wp[4], wp[5], wp[6], wp[7],
        wp[8], wp[9], wp[10], wp[11],
        wp[12], wp[13], wp[14], wp[15],
        wp[16], wp[17], wp[18], wp[19],
        ow, ob, out);
  }
}

// Round 12
// 785.904 us; speedup vs baseline: 1.6349x; 1.0098x over previous
//
#include <hip/hip_runtime.h>

typedef short s16x8 __attribute__((ext_vector_type(8)));
typedef short s16x4 __attribute__((ext_vector_type(4)));
typedef float f32x4 __attribute__((ext_vector_type(4)));
typedef unsigned int u32;
typedef unsigned short u16;

#define NT 512
#define DD 64
#define NTH 512

#define CHUNK 1024

// ---------- recurrent kernel LDS (5 h-chunks per parity) ----------
#define P2STRIDE (5*CHUNK)
#define PH0 0
#define PH1 CHUNK
#define PH2 (2*CHUNK)
#define PH3 (3*CHUNK)
#define PH4 (4*CHUNK)
#define FRTOT2 (2*P2STRIDE)   // 10240 u16 = 20 KB
#define NSTEP2 520            // 512 + 8 pipeline stages (mixed deferral)

// ---------- fallback (round-3) LDS ----------
#define PSTRIDE (7*CHUNK)
#define XIN0 0
#define H0C (2*CHUNK)
#define H1C (3*CHUNK)
#define H2C (4*CHUNK)
#define H3C (5*CHUNK)
#define H4C (6*CHUNK)
#define FRTOT (2*PSTRIDE)
#define NSTEP_FB 517

#define MFMA16(A,B,C) __builtin_amdgcn_mfma_f32_16x16x32_bf16(A,B,C,0,0,0)

__device__ __forceinline__ float sigf(float x){ return 1.0f/(1.0f+__expf(-x)); }
__device__ __forceinline__ float tanhf2(float x){ return 2.0f/(1.0f+__expf(-2.0f*x)) - 1.0f; }

__device__ __forceinline__ u16 f2bf(float f) {
  u32 u = __builtin_bit_cast(u32, f);
  return (u16)((u + 0x7fffu + ((u >> 16) & 1u)) >> 16);
}
__device__ __forceinline__ float bf2f(u16 h) {
  u32 u = ((u32)h) << 16;
  return __builtin_bit_cast(float, u);
}

// barrier WITHOUT the vmcnt(0) drain: LDS visibility only (global ops drain at use)
__device__ __forceinline__ void soft_barrier() {
  asm volatile("s_waitcnt lgkmcnt(0)" ::: "memory");
  __builtin_amdgcn_s_barrier();
  asm volatile("" ::: "memory");
}

// wait own LDS writes before own read-back (RAW through LDS within a wave)
__device__ __forceinline__ void lds_fence() {
  asm volatile("s_waitcnt lgkmcnt(0)" ::: "memory");
}

__device__ __forceinline__ u32 cvtpk_bf16(float a, float b) {
  u32 r;
  asm("v_cvt_pk_bf16_f32 %0, %1, %2" : "=v"(r) : "v"(a), "v"(b));
  return r;
}

// xor-8 lane swizzle (within 32-lane half): partner = lane ^ 8
__device__ __forceinline__ float swzf(float v) {
  return __builtin_bit_cast(float,
      __builtin_amdgcn_ds_swizzle(__builtin_bit_cast(int, v), 0x201F));
}

// A-fragment (standard hi/lo pair): lane holds A[row0+(lane&15)][kbase+(lane>>4)*8+e]
__device__ __forceinline__ void load_wfrag(const float* __restrict__ W, int row0, int nrow, int din,
                                           int kbase, int lane, s16x8& hi, s16x8& lo)
{
  const int m = lane & 15, kb = lane >> 4;
#pragma unroll
  for (int e = 0; e < 8; ++e) {
    int k = kbase + kb*8 + e;
    float v = (m < nrow && k < din) ? W[(size_t)(row0 + m)*din + k] : 0.0f;
    u16 h = f2bf(v);
    hi[e] = (short)h;
    lo[e] = (short)f2bf(v - bf2f(h));
  }
}

// Packed A-fragment for real K <= 16: q=0,1 hold hi[k=(q&1)*8+e], q=2,3 hold lo.
__device__ __forceinline__ void load_wfrag_pk(const float* __restrict__ W, int row0, int nrow,
                                              int stride, int KR, int lane, s16x8& A1)
{
  const int m = lane & 15, q = lane >> 4;
  const bool lohalf = q >= 2;
  const int kb = (q & 1) * 8;
#pragma unroll
  for (int e = 0; e < 8; ++e) {
    int k = kb + e;
    float v = (m < nrow && k < KR) ? W[(size_t)(row0 + m)*stride + k] : 0.0f;
    u16 h = f2bf(v);
    A1[e] = (short)(lohalf ? f2bf(v - bf2f(h)) : h);
  }
}

// B-fragment read (standard): hi at +0, lo at +128 within each 256-u16 k-block
__device__ __forceinline__ void read_b(const u16* base, int lane, s16x8& hi, s16x8& lo)
{
  const int off = ((lane >> 4) << 8) + ((lane & 15) << 3);
  hi = *(const s16x8*)(base + off);
  lo = *(const s16x8*)(base + off + 128);
}

// Packed B read for real K <= 16: b1 = [hi|lo], b2 = halves crossed (addr ^ 128).
__device__ __forceinline__ void read_b_pk(const u16* base, int lane, s16x8& b1, s16x8& b2)
{
  const int q = lane >> 4;
  const int off1 = ((q & 1) << 8) + ((q >> 1) << 7) + ((lane & 15) << 3);
  b1 = *(const s16x8*)(base + off1);
  b2 = *(const s16x8*)(base + (off1 ^ 128));
}

// Lane-split combine: lanes bb<8 take j-pair {q*4,q*4+1}, lanes bb>=8 take
// {q*4+2,q*4+3} of batch bb-8 via xor-8 swizzle (phantom cols repurposed).
// Halves exp/rcp count. All 64 lanes write (128 h-values = 16 j x 8 bb).
template<bool NI_OWN>
__device__ __forceinline__ void combine_split8(
    f32x4 aR, f32x4 aZ, f32x4 aNi, f32x4 aNh,
    float (&hp)[2], u16* dstC, int jbase, int nrow, int lane)
{
  const int bb = lane & 15, q = lane >> 4;
  const bool hih = (bb & 8) != 0;
  float sR2 = swzf(aR[2]),  sR3 = swzf(aR[3]);
  float sZ2 = swzf(aZ[2]),  sZ3 = swzf(aZ[3]);
  float sH2 = swzf(aNh[2]), sH3 = swzf(aNh[3]);
  float r0  = hih ? sR2 : aR[0],  r1  = hih ? sR3 : aR[1];
  float z0  = hih ? sZ2 : aZ[0],  z1  = hih ? sZ3 : aZ[1];
  float nh0 = hih ? sH2 : aNh[0], nh1 = hih ? sH3 : aNh[1];
  float ni0, ni1;
  if constexpr (NI_OWN) {          // aNi duplicated across lane / lane^8 (gi regs)
    ni0 = hih ? aNi[2] : aNi[0];
    ni1 = hih ? aNi[3] : aNi[1];
  } else {
    float sN2 = swzf(aNi[2]), sN3 = swzf(aNi[3]);
    ni0 = hih ? sN2 : aNi[0];
    ni1 = hih ? sN3 : aNi[1];
  }
  float rr0 = sigf(r0), rr1 = sigf(r1);
  float zz0 = sigf(z0), zz1 = sigf(z1);
  float n0 = tanhf2(ni0 + rr0*nh0), n1 = tanhf2(ni1 + rr1*nh1);
  float h0 = (1.0f - zz0)*n0 + zz0*hp[0];
  float h1 = (1.0f - zz1)*n1 + zz1*hp[1];
  hp[0] = h0; hp[1] = h1;
  const int jj = q*4 + (hih ? 2 : 0);
  if (jj < nrow) {
    const int j = jbase + jj;
    u32 ph = cvtpk_bf16(h0, h1);
    float f0 = h0 - __builtin_bit_cast(float, ph << 16);
    float f1 = h1 - __builtin_bit_cast(float, ph & 0xffff0000u);
    u32 pl = cvtpk_bf16(f0, f1);
    u16* dst = dstC + ((j >> 3) << 8) + ((bb & 7) << 3) + (j & 7);
    *(u32*)dst = ph;
    *(u32*)(dst + 128) = pl;
  }
}

// =====================================================================
// Phase 1: gi0[b][t][96] = Wih0 @ x_imp(b,t) + bih0 (+bhh0 for r,z rows)
// v2: float4 global loads; separated hi/lo u16 LDS planes (stride 72,
// 16B-aligned, 2-way bank alias = free) -> ds_read_b128 B-frags, no unpack.
// =====================================================================
#define XSS 72
__global__ __launch_bounds__(256)
void gi0_gemm(const float* __restrict__ X, const float* __restrict__ M, const float* __restrict__ L,
              const float* __restrict__ wih0, const float* __restrict__ bih0,
              const float* __restrict__ bhh0,
              float* __restrict__ gi)
{
  __shared__ __align__(16) u16 xh[128*XSS];
  __shared__ __align__(16) u16 xl[128*XSS];
  const int tid = threadIdx.x;
  const int wv = tid >> 6, lane = tid & 63;
  const int q = lane >> 4;
  const int b = blockIdx.x >> 2;
  const int t0 = (blockIdx.x & 3) * 128;
  const size_t base = ((size_t)b*NT + t0)*DD;

  const float4* X4 = (const float4*)(X + base);
  const float4* M4 = (const float4*)(M + base);
  const float4* L4 = (const float4*)(L + base);
#pragma unroll
  for (int k = 0; k < 8; ++k) {
    const int i4 = tid + k*256;          // float4 index; element i = 4*i4
    float4 x = X4[i4], m = M4[i4], l = L4[i4];
    const int t = (i4 >> 4), d = (i4 & 15) << 2;
    float v0 = x.x*m.x + l.x*(1.0f - m.x);
    float v1 = x.y*m.y + l.y*(1.0f - m.y);
    float v2 = x.z*m.z + l.z*(1.0f - m.z);
    float v3 = x.w*m.w + l.w*(1.0f - m.w);
    u16 h0 = f2bf(v0), h1 = f2bf(v1), h2 = f2bf(v2), h3 = f2bf(v3);
    s16x4 hv; hv[0] = (short)h0; hv[1] = (short)h1; hv[2] = (short)h2; hv[3] = (short)h3;
    s16x4 lv;
    lv[0] = (short)f2bf(v0 - bf2f(h0));
    lv[1] = (short)f2bf(v1 - bf2f(h1));
    lv[2] = (short)f2bf(v2 - bf2f(h2));
    lv[3] = (short)f2bf(v3 - bf2f(h3));
    *(s16x4*)&xh[t*XSS + d] = hv;
    *(s16x4*)&xl[t*XSS + d] = lv;
  }

  s16x8 Ah[6][2], Al[6][2];
  f32x4 cb[6];
#pragma unroll
  for (int tile = 0; tile < 6; ++tile) {
#pragma unroll
    for (int c = 0; c < 2; ++c)
      load_wfrag(wih0, tile*16, 16, 64, c*32, lane, Ah[tile][c], Al[tile][c]);
#pragma unroll
    for (int i = 0; i < 4; ++i) {
      int row = tile*16 + q*4 + i;
      float bv = bih0[row];
      if (tile < 4) bv += bhh0[row];
      cb[tile][i] = bv;
    }
  }
  __syncthreads();

#pragma unroll
  for (int g2 = 0; g2 < 2; ++g2) {
    const int tloc = g2*64 + wv*16 + (lane & 15);
    s16x8 Bh[2], Bl[2];
#pragma unroll
    for (int c = 0; c < 2; ++c) {
      Bh[c] = *(const s16x8*)&xh[tloc*XSS + c*32 + q*8];
      Bl[c] = *(const s16x8*)&xl[tloc*XSS + c*32 + q*8];
    }
    float* gp = gi + ((size_t)b*NT + t0 + tloc)*96 + q*4;
#pragma unroll
    for (int tile = 0; tile < 6; ++tile) {
      f32x4 acc = cb[tile];
#pragma unroll
      for (int c = 0; c < 2; ++c) {
        acc = MFMA16(Ah[tile][c], Bh[c], acc);
        acc = MFMA16(Ah[tile][c], Bl[c], acc);
        acc = MFMA16(Al[tile][c], Bh[c], acc);
      }
      *(f32x4*)(gp + tile*16) = acc;
    }
  }
}

// =====================================================================
// Phase 2: mixed-schedule recurrent kernel (unchanged from R11).
//  - L0 (w0/w1, j-split) and L4 (w3/w6, j-split): NON-deferred.
//  - L1/L2/L3 (single-wave): deferred combine.
//  Offsets: h0(t)@t, h1(t)@t+2, h2(t)@t+4, h3(t)@t+6, h4(t)@t+7, OUT@t+8.
// =====================================================================
__device__ __forceinline__ void wave_l0(
    const float* __restrict__ Whh, const float* __restrict__ bhh,
    const float* __restrict__ gi, int jbase,
    u16* FRu, int b0, int lane)
{
  s16x8 Ahh[3], Ahl[3];
#pragma unroll
  for (int g = 0; g < 3; ++g)
    load_wfrag(Whh, g*32 + jbase, 16, 32, 0, lane, Ahh[g], Ahl[g]);
  const int q = lane >> 4;
  f32x4 cNh;
#pragma unroll
  for (int i = 0; i < 4; ++i) cNh[i] = bhh[64 + jbase + q*4 + i];
  float hp[2] = {0.f, 0.f};

  const float* gb = gi + (size_t)(b0 + (lane & 7)) * ((size_t)NT*96) + jbase + q*4;
  f32x4 AR, AZ, AN, BR, BZ, BN;
  AR = *(const f32x4*)(gb);      AZ = *(const f32x4*)(gb+32);  AN = *(const f32x4*)(gb+64);
  BR = *(const f32x4*)(gb+96);   BZ = *(const f32x4*)(gb+128); BN = *(const f32x4*)(gb+160);

  auto body = [&](int st, const u16* R, u16* Wp, f32x4& gR, f32x4& gZ, f32x4& gN) {
    if (st < NT) {
      f32x4 aR = gR, aZ = gZ, aNi = gN, aNh = cNh;   // biases pre-folded in gi
      s16x8 bh_, bl_;
      read_b(R + PH0, lane, bh_, bl_);   // h0(t-1): written LAST step (race-free)
      aR  = MFMA16(Ahh[0], bh_, aR);  aR  = MFMA16(Ahh[0], bl_, aR);  aR  = MFMA16(Ahl[0], bh_, aR);
      aZ  = MFMA16(Ahh[1], bh_, aZ);  aZ  = MFMA16(Ahh[1], bl_, aZ);  aZ  = MFMA16(Ahl[1], bh_, aZ);
      aNh = MFMA16(Ahh[2], bh_, aNh); aNh = MFMA16(Ahh[2], bl_, aNh); aNh = MFMA16(Ahl[2], bh_, aNh);
      combine_split8<true>(aR, aZ, aNi, aNh, hp, Wp + PH0, jbase, 16, lane);
    }
    if (st + 2 < NT) {
      const float* p = gb + (size_t)(st + 2)*96;
      gR = *(const f32x4*)(p); gZ = *(const f32x4*)(p+32); gN = *(const f32x4*)(p+64);
    }
  };

  for (int s = 0; s < NSTEP2; s += 2) {
    body(s,     FRu + P2STRIDE, FRu,            AR, AZ, AN);  // rp=1, par=0
    soft_barrier();
    body(s + 1, FRu,            FRu + P2STRIDE, BR, BZ, BN);  // rp=0, par=1
    soft_barrier();
  }
}

// NON-deferred mid wave (used for j-split L4): reads x and own h(t-1) from rp.
template<int DIN, int DH, bool PKX, bool PKH>
__device__ __forceinline__ void wave_mid_nd(
    const float* __restrict__ Wih, const float* __restrict__ Whh,
    const float* __restrict__ bih, const float* __restrict__ bhh,
    int jbase, int xc, int hc, int s0, int s1,
    u16* FRu, int lane)
{
  const int nrow = (DH - jbase) < 16 ? (DH - jbase) : 16;
  s16x8 Ax1[3], Axh[3], Axl[3], Ah1[3], Ahh[3], Ahl[3];
#pragma unroll
  for (int g = 0; g < 3; ++g) {
    if constexpr (PKX) load_wfrag_pk(Wih, g*DH + jbase, nrow, DIN, DIN, lane, Ax1[g]);
    else               load_wfrag(Wih, g*DH + jbase, nrow, DIN, 0, lane, Axh[g], Axl[g]);
    if constexpr (PKH) load_wfrag_pk(Whh, g*DH + jbase, nrow, DH, DH, lane, Ah1[g]);
    else               load_wfrag(Whh, g*DH + jbase, nrow, DH, 0, lane, Ahh[g], Ahl[g]);
  }
  const int q = lane >> 4;
  f32x4 cR, cZ, cNi, cNh;
#pragma unroll
  for (int i = 0; i < 4; ++i) {
    int lr = q*4 + i;
    int j = jbase + lr;
    bool jr = lr < nrow;
    cR[i]  = jr ? bih[j] + bhh[j] : 0.f;
    cZ[i]  = jr ? bih[DH+j] + bhh[DH+j] : 0.f;
    cNi[i] = jr ? bih[2*DH+j] : 0.f;
    cNh[i] = jr ? bhh[2*DH+j] : 0.f;
  }
  float hp[2] = {0.f, 0.f};

  auto body = [&](int st, const u16* R, u16* Wp) {
    if (st >= s0 && st <= s1) {
      f32x4 aR = cR, aZ = cZ, aNi = cNi, aNh = cNh;
      if constexpr (PKX) {
        s16x8 b1, b2;
        read_b_pk(R + xc, lane, b1, b2);
        aR  = MFMA16(Ax1[0], b1, aR);  aR  = MFMA16(Ax1[0], b2, aR);
        aZ  = MFMA16(Ax1[1], b1, aZ);  aZ  = MFMA16(Ax1[1], b2, aZ);
        aNi = MFMA16(Ax1[2], b1, aNi); aNi = MFMA16(Ax1[2], b2, aNi);
      } else {
        s16x8 bh_, bl_;
        read_b(R + xc, lane, bh_, bl_);
        aR  = MFMA16(Axh[0], bh_, aR);  aR  = MFMA16(Axh[0], bl_, aR);  aR  = MFMA16(Axl[0], bh_, aR);
        aZ  = MFMA16(Axh[1], bh_, aZ);  aZ  = MFMA16(Axh[1], bl_, aZ);  aZ  = MFMA16(Axl[1], bh_, aZ);
        aNi = MFMA16(Axh[2], bh_, aNi); aNi = MFMA16(Axh[2], bl_, aNi); aNi = MFMA16(Axl[2], bh_, aNi);
      }
      if constexpr (PKH) {
        s16x8 b1, b2;
        read_b_pk(R + hc, lane, b1, b2);   // h(t-1): written LAST step (race-free)
        aR  = MFMA16(Ah1[0], b1, aR);  aR  = MFMA16(Ah1[0], b2, aR);
        aZ  = MFMA16(Ah1[1], b1, aZ);  aZ  = MFMA16(Ah1[1], b2, aZ);
        aNh = MFMA16(Ah1[2], b1, aNh); aNh = MFMA16(Ah1[2], b2, aNh);
      } else {
        s16x8 bh_, bl_;
        read_b(R + hc, lane, bh_, bl_);
        aR  = MFMA16(Ahh[0], bh_, aR);  aR  = MFMA16(Ahh[0], bl_, aR);  aR  = MFMA16(Ahl[0], bh_, aR);
        aZ  = MFMA16(Ahh[1], bh_, aZ);  aZ  = MFMA16(Ahh[1], bl_, aZ);  aZ  = MFMA16(Ahl[1], bh_, aZ);
        aNh = MFMA16(Ahh[2], bh_, aNh); aNh = MFMA16(Ahh[2], bl_, aNh); aNh = MFMA16(Ahl[2], bh_, aNh);
      }
      combine_split8<false>(aR, aZ, aNi, aNh, hp, Wp + hc, jbase, nrow, lane);
    }
  };

  for (int s = 0; s < NSTEP2; s += 2) {
    body(s,     FRu + P2STRIDE, FRu);            // rp=1, par=0
    soft_barrier();
    body(s + 1, FRu,            FRu + P2STRIDE); // rp=0, par=1
    soft_barrier();
  }
}

// DEFERRED mid wave (single-wave layers only): combine(t-1) this step, then
// own-wave readback of just-written h(t-1) (same-wave DS in-order).
template<int DIN, int DH, bool PKX, bool PKH>
__device__ __forceinline__ void wave_mid_df(
    const float* __restrict__ Wih, const float* __restrict__ Whh,
    const float* __restrict__ bih, const float* __restrict__ bhh,
    int jbase, int xc, int hc, int s0,
    u16* FRu, int lane)
{
  const int nrow = (DH - jbase) < 16 ? (DH - jbase) : 16;
  s16x8 Ax1[3], Axh[3], Axl[3], Ah1[3], Ahh[3], Ahl[3];
#pragma unroll
  for (int g = 0; g < 3; ++g) {
    if constexpr (PKX) load_wfrag_pk(Wih, g*DH + jbase, nrow, DIN, DIN, lane, Ax1[g]);
    else               load_wfrag(Wih, g*DH + jbase, nrow, DIN, 0, lane, Axh[g], Axl[g]);
    if constexpr (PKH) load_wfrag_pk(Whh, g*DH + jbase, nrow, DH, DH, lane, Ah1[g]);
    else               load_wfrag(Whh, g*DH + jbase, nrow, DH, 0, lane, Ahh[g], Ahl[g]);
  }
  const int q = lane >> 4;
  f32x4 cR, cZ, cNi, cNh;
#pragma unroll
  for (int i = 0; i < 4; ++i) {
    int lr = q*4 + i;
    int j = jbase + lr;
    bool jr = lr < nrow;
    cR[i]  = jr ? bih[j] + bhh[j] : 0.f;
    cZ[i]  = jr ? bih[DH+j] + bhh[DH+j] : 0.f;
    cNi[i] = jr ? bih[2*DH+j] : 0.f;
    cNh[i] = jr ? bhh[2*DH+j] : 0.f;
  }
  f32x4 accR = {}, accZ = {}, accNi = {}, accNh = {};
  float hp[2] = {0.f, 0.f};

  auto body = [&](int st, const u16* R, u16* Wp) {
    const bool compute = (st >= s0) && (st <= s0 + 511);
    const bool docomb  = (st >= s0 + 1) && (st <= s0 + 512);
    f32x4 nR, nZ, nNi, nNh;
    if (compute) {
      nR = cR; nZ = cZ; nNi = cNi; nNh = cNh;
      if constexpr (PKX) {
        s16x8 b1, b2;
        read_b_pk(R + xc, lane, b1, b2);
        nR  = MFMA16(Ax1[0], b1, nR);  nR  = MFMA16(Ax1[0], b2, nR);
        nZ  = MFMA16(Ax1[1], b1, nZ);  nZ  = MFMA16(Ax1[1], b2, nZ);
        nNi = MFMA16(Ax1[2], b1, nNi); nNi = MFMA16(Ax1[2], b2, nNi);
      } else {
        s16x8 bh_, bl_;
        read_b(R + xc, lane, bh_, bl_);
        nR  = MFMA16(Axh[0], bh_, nR);  nR  = MFMA16(Axh[0], bl_, nR);  nR  = MFMA16(Axl[0], bh_, nR);
        nZ  = MFMA16(Axh[1], bh_, nZ);  nZ  = MFMA16(Axh[1], bl_, nZ);  nZ  = MFMA16(Axl[1], bh_, nZ);
        nNi = MFMA16(Axh[2], bh_, nNi); nNi = MFMA16(Axh[2], bl_, nNi); nNi = MFMA16(Axl[2], bh_, nNi);
      }
    }
    if (docomb) {
      combine_split8<false>(accR, accZ, accNi, accNh, hp, Wp + hc, jbase, nrow, lane);
      lds_fence();
    }
    if (compute) {
      if constexpr (PKH) {
        s16x8 b1, b2;
        read_b_pk(Wp + hc, lane, b1, b2);   // own just-written h(t-1)
        nR  = MFMA16(Ah1[0], b1, nR);  nR  = MFMA16(Ah1[0], b2, nR);
        nZ  = MFMA16(Ah1[1], b1, nZ);  nZ  = MFMA16(Ah1[1], b2, nZ);
        nNh = MFMA16(Ah1[2], b1, nNh); nNh = MFMA16(Ah1[2], b2, nNh);
      } else {
        s16x8 bh_, bl_;
        read_b(Wp + hc, lane, bh_, bl_);
        nR  = MFMA16(Ahh[0], bh_, nR);  nR  = MFMA16(Ahh[0], bl_, nR);  nR  = MFMA16(Ahl[0], bh_, nR);
        nZ  = MFMA16(Ahh[1], bh_, nZ);  nZ  = MFMA16(Ahh[1], bl_, nZ);  nZ  = MFMA16(Ahl[1], bh_, nZ);
        nNh = MFMA16(Ahh[2], bh_, nNh); nNh = MFMA16(Ahh[2], bl_, nNh); nNh = MFMA16(Ahl[2], bh_, nNh);
      }
      accR = nR; accZ = nZ; accNi = nNi; accNh = nNh;
    }
  };

  for (int s = 0; s < NSTEP2; s += 2) {
    body(s,     FRu + P2STRIDE, FRu);            // rp=1, par=0
    soft_barrier();
    body(s + 1, FRu,            FRu + P2STRIDE); // rp=0, par=1
    soft_barrier();
  }
}

__device__ __forceinline__ void wave_out2(
    const float* __restrict__ OW, const float* __restrict__ OBb,
    u16* FRu, float* __restrict__ out, int b0, int lane)
{
  s16x8 Oh[4], Ol[4];
  f32x4 cO[4];
  const int q = lane >> 4, bb = lane & 15;
#pragma unroll
  for (int t4 = 0; t4 < 4; ++t4) {
    load_wfrag(OW, t4*16, 16, 32, 0, lane, Oh[t4], Ol[t4]);
#pragma unroll
    for (int i = 0; i < 4; ++i) cO[t4][i] = OBb[t4*16 + q*4 + i];
  }
  float* ob = out + ((size_t)(b0 + (bb & 7))*NT)*DD + q*4;

  auto emit = [&](int st, const u16* R) {
    if (st >= 8 && st <= 519) {   // h4(t), t = st-8, written at step st-1
      s16x8 bh_, bl_;
      read_b(R + PH4, lane, bh_, bl_);
#pragma unroll
      for (int t4 = 0; t4 < 4; ++t4) {
        f32x4 a_ = cO[t4];
        a_ = MFMA16(Oh[t4], bh_, a_); a_ = MFMA16(Oh[t4], bl_, a_); a_ = MFMA16(Ol[t4], bh_, a_);
        if (bb < 8) *(f32x4*)(ob + t4*16) = a_;   // direct C-frag store
      }
      ob += DD;
    }
  };

  for (int s = 0; s < NSTEP2; s += 2) {
    emit(s,     FRu + P2STRIDE);   // rp=1
    soft_barrier();
    emit(s + 1, FRu);              // rp=0
    soft_barrier();
  }
}

__global__ __launch_bounds__(NTH, 1)
void gru_rec(const float* __restrict__ gi,
             const float* __restrict__ whh0, const float* __restrict__ bhh0,
             const float* __restrict__ wih1, const float* __restrict__ whh1, const float* __restrict__ bih1, const float* __restrict__ bhh1,
             const float* __restrict__ wih2, const float* __restrict__ whh2, const float* __restrict__ bih2, const float* __restrict__ bhh2,
             const float* __restrict__ wih3, const float* __restrict__ whh3, const float* __restrict__ bih3, const float* __restrict__ bhh3,
             const float* __restrict__ wih4, const float* __restrict__ whh4, const float* __restrict__ bih4, const float* __restrict__ bhh4,
             const float* __restrict__ out_w, const float* __restrict__ out_b,
             float* __restrict__ out)
{
  __shared__ __align__(16) u16 FRu[FRTOT2];
  const int tid = threadIdx.x;
  const int w = tid >> 6, lane = tid & 63;
  const int b0 = blockIdx.x * 8;

  for (int i = tid; i < FRTOT2; i += NTH) FRu[i] = 0;
  __syncthreads();

  if (w == 0)
    wave_l0(whh0, bhh0, gi,  0, FRu, b0, lane);                                 // h0(t)@t
  else if (w == 1)
    wave_l0(whh0, bhh0, gi, 16, FRu, b0, lane);
  else if (w == 2)
    wave_mid_df<32,16,false,true >(wih1,whh1,bih1,bhh1,  0, PH0, PH1, 1, FRu, lane);  // h1(t)@t+2
  else if (w == 4)
    wave_mid_df<16, 8,true ,true >(wih2,whh2,bih2,bhh2,  0, PH1, PH2, 3, FRu, lane);  // h2(t)@t+4
  else if (w == 5)
    wave_mid_df< 8,16,true ,true >(wih3,whh3,bih3,bhh3,  0, PH2, PH3, 5, FRu, lane);  // h3(t)@t+6
  else if (w == 3)
    wave_mid_nd<16,32,true ,false>(wih4,whh4,bih4,bhh4,  0, PH3, PH4, 7, 518, FRu, lane);  // h4(t)@t+7
  else if (w == 6)
    wave_mid_nd<16,32,true ,false>(wih4,whh4,bih4,bhh4, 16, PH3, PH4, 7, 518, FRu, lane);
  else
    wave_out2(out_w, out_b, FRu, out, b0, lane);                                 // out(t)@t+8
}

// =====================================================================
// Fallback: round-3 kernel (used only if ws_size is too small for gi0)
// =====================================================================
__device__ __forceinline__ void combine_write(
    f32x4 aR, f32x4 aZ, f32x4 aNi, f32x4 aNh,
    float (&hprev)[4], u16* hdst_base, int jbase, int nrow, int lane)
{
  const int bb = lane & 15, q = lane >> 4;
  float hv[4];
#pragma unroll
  for (int i = 0; i < 4; ++i) {
    float rr = sigf(aR[i]);
    float zz = sigf(aZ[i]);
    float nn = tanhf2(aNi[i] + rr*aNh[i]);
    hv[i] = (1.0f - zz)*nn + zz*hprev[i];
    hprev[i] = hv[i];
  }
  if (bb < 8 && q*4 < nrow) {
    const int j = jbase + q*4;
    const int kb = j >> 3, e = j & 7;
    s16x4 hh, ll;
#pragma unroll
    for (int i = 0; i < 4; ++i) {
      u16 h = f2bf(hv[i]);
      hh[i] = (short)h;
      ll[i] = (short)f2bf(hv[i] - bf2f(h));
    }
    u16* dst = hdst_base + kb*256 + bb*8 + e;
    *(s16x4*)dst = hh;
    *(s16x4*)(dst + 128) = ll;
  }
}

__device__ __forceinline__ void write_x(u16* FRu, int par, int w, int lane, float v)
{
  const int d = lane;
  const int chunk = d >> 5, kb = (d >> 3) & 3, e = d & 7;
  u16 h = f2bf(v);
  u16 l2 = f2bf(v - bf2f(h));
  u16* p = FRu + par*PSTRIDE + XIN0 + chunk*CHUNK + kb*256 + w*8 + e;
  p[0] = h; p[128] = l2;
}

template<int DIN, int DH, int NXC>
__device__ __forceinline__ void wave_gru_fb(
    const float* __restrict__ Wih, const float* __restrict__ Whh,
    const float* __restrict__ bih, const float* __restrict__ bhh,
    int jbase, int xc, int hc, int s0, int s1,
    u16* FRu, float* OST,
    const float* __restrict__ X, const float* __restrict__ Mm, const float* __restrict__ Ll,
    float* __restrict__ out, int b0, int w, int lane)
{
  const int nrow = (DH - jbase) < 16 ? (DH - jbase) : 16;
  s16x8 Axh[3][NXC], Axl[3][NXC], Ahh[3], Ahl[3];
#pragma unroll
  for (int g = 0; g < 3; ++g) {
#pragma unroll
    for (int c = 0; c < NXC; ++c)
      load_wfrag(Wih, g*DH + jbase, nrow, DIN, c*32, lane, Axh[g][c], Axl[g][c]);
    load_wfrag(Whh, g*DH + jbase, nrow, DH, 0, lane, Ahh[g], Ahl[g]);
  }
  f32x4 cR, cZ, cNi, cNh;
  {
    const int q = lane >> 4;
#pragma unroll
    for (int i = 0; i < 4; ++i) {
      int lr = q*4 + i;
      int j = jbase + lr;
      bool jr = lr < nrow;
      cR[i]  = jr ? bih[j] + bhh[j] : 0.f;
      cZ[i]  = jr ? bih[DH+j] + bhh[DH+j] : 0.f;
      cNi[i] = jr ? bih[2*DH+j] : 0.f;
      cNh[i] = jr ? bhh[2*DH+j] : 0.f;
    }
  }
  float hprev[4] = {0.f, 0.f, 0.f, 0.f};

  const size_t gbase = ((size_t)(b0 + w))*((size_t)NT*DD) + lane;
  float rx = X[gbase], rm = Mm[gbase], rl = Ll[gbase];
  write_x(FRu, 1, w, lane, rx*rm + rl*(1.0f - rm));
  rx = X[gbase + DD]; rm = Mm[gbase + DD]; rl = Ll[gbase + DD];
  __syncthreads();

  for (int s = 0; s < NSTEP_FB; ++s) {
    const int par = s & 1, rp = par ^ 1;
    float nx = 0.f, nm = 0.f, nl = 0.f;
    if (s <= 509) {
      size_t g = gbase + (size_t)(s+2)*DD;
      nx = X[g]; nm = Mm[g]; nl = Ll[g];
    }
    f32x4 aR = cR, aZ = cZ, aNi = cNi, aNh = cNh;
    const bool run = (s >= s0) && (s <= s1);
    if (run) {
      const u16* RB = FRu + rp*PSTRIDE;
      s16x8 bh_, bl_;
#pragma unroll
      for (int c = 0; c < NXC; ++c) {
        read_b(RB + xc + c*CHUNK, lane, bh_, bl_);
        aR  = MFMA16(Axh[0][c], bh_, aR);  aR  = MFMA16(Axh[0][c], bl_, aR);  aR  = MFMA16(Axl[0][c], bh_, aR);
        aZ  = MFMA16(Axh[1][c], bh_, aZ);  aZ  = MFMA16(Axh[1][c], bl_, aZ);  aZ  = MFMA16(Axl[1][c], bh_, aZ);
        aNi = MFMA16(Axh[2][c], bh_, aNi); aNi = MFMA16(Axh[2][c], bl_, aNi); aNi = MFMA16(Axl[2][c], bh_, aNi);
      }
      read_b(RB + hc, lane, bh_, bl_);
      aR  = MFMA16(Ahh[0], bh_, aR);  aR  = MFMA16(Ahh[0], bl_, aR);  aR  = MFMA16(Ahl[0], bh_, aR);
      aZ  = MFMA16(Ahh[1], bh_, aZ);  aZ  = MFMA16(Ahh[1], bl_, aZ);  aZ  = MFMA16(Ahl[1], bh_, aZ);
      aNh = MFMA16(Ahh[2], bh_, aNh); aNh = MFMA16(Ahh[2], bl_, aNh); aNh = MFMA16(Ahl[2], bh_, aNh);
    }
    __syncthreads();

    if (run)
      combine_write(aR, aZ, aNi, aNh, hprev, FRu + par*PSTRIDE + hc, jbase, nrow, lane);
    if (s >= 5)
      out[((size_t)(b0 + w)*NT + (s-5))*DD + lane] = OST[w*65 + lane];
    if (s <= 510) write_x(FRu, par, w, lane, rx*rm + rl*(1.0f - rm));
    rx = nx; rm = nm; rl = nl;
    __syncthreads();
  }
}

__device__ __forceinline__ void wave_out_fb(
    const float* __restrict__ OW, const float* __restrict__ OBb,
    u16* FRu, float* OST,
    const float* __restrict__ X, const float* __restrict__ Mm, const float* __restrict__ Ll,
    float* __restrict__ out, int b0, int w, int lane)
{
  s16x8 Oh[4], Ol[4];
  f32x4 cO[4];
#pragma unroll
  for (int t4 = 0; t4 < 4; ++t4) {
    load_wfrag(OW, t4*16, 16, 32, 0, lane, Oh[t4], Ol[t4]);
#pragma unroll
    for (int i = 0; i < 4; ++i) cO[t4][i] = OBb[t4*16 + (lane>>4)*4 + i];
  }
  const size_t gbase = ((size_t)(b0 + w))*((size_t)NT*DD) + lane;
  float rx = X[gbase], rm = Mm[gbase], rl = Ll[gbase];
  write_x(FRu, 1, w, lane, rx*rm + rl*(1.0f - rm));
  rx = X[gbase + DD]; rm = Mm[gbase + DD]; rl = Ll[gbase + DD];
  __syncthreads();

  for (int s = 0; s < NSTEP_FB; ++s) {
    const int par = s & 1, rp = par ^ 1;
    float nx = 0.f, nm = 0.f, nl = 0.f;
    if (s <= 509) { size_t g = gbase + (size_t)(s+2)*DD; nx = X[g]; nm = Mm[g]; nl = Ll[g]; }
    if (s >= 5) {
      s16x8 bh_, bl_;
      read_b(FRu + rp*PSTRIDE + H4C, lane, bh_, bl_);
      const int bb = lane & 15, q = lane >> 4;
#pragma unroll
      for (int t4 = 0; t4 < 4; ++t4) {
        f32x4 a_ = cO[t4];
        a_ = MFMA16(Oh[t4], bh_, a_); a_ = MFMA16(Oh[t4], bl_, a_); a_ = MFMA16(Ol[t4], bh_, a_);
        if (bb < 8) {
#pragma unroll
          for (int i = 0; i < 4; ++i) OST[bb*65 + t4*16 + q*4 + i] = a_[i];
        }
      }
    }
    __syncthreads();
    if (s >= 5)
      out[((size_t)(b0 + w)*NT + (s-5))*DD + lane] = OST[w*65 + lane];
    if (s <= 510) write_x(FRu, par, w, lane, rx*rm + rl*(1.0f - rm));
    rx = nx; rm = nm; rl = nl;
    __syncthreads();
  }
}

__global__ __launch_bounds__(NTH, 1)
void gru_mfma(const float* __restrict__ X, const float* __restrict__ M, const float* __restrict__ L,
              const float* __restrict__ wih0, const float* __restrict__ whh0, const float* __restrict__ bih0, const float* __restrict__ bhh0,
              const float* __restrict__ wih1, const float* __restrict__ whh1, const float* __restrict__ bih1, const float* __restrict__ bhh1,
              const float* __restrict__ wih2, const float* __restrict__ whh2, const float* __restrict__ bih2, const float* __restrict__ bhh2,
              const float* __restrict__ wih3, const float* __restrict__ whh3, const float* __restrict__ bih3, const float* __restrict__ bhh3,
              const float* __restrict__ wih4, const float* __restrict__ whh4, const float* __restrict__ bih4, const float* __restrict__ bhh4,
              const float* __restrict__ out_w, const float* __restrict__ out_b,
              float* __restrict__ out)
{
  __shared__ __align__(16) u16 FRu[FRTOT];
  __shared__ float OST[8*65];
  const int tid = threadIdx.x;
  const int w = tid >> 6, lane = tid & 63;
  const int b0 = blockIdx.x * 8;

  for (int i = tid; i < FRTOT; i += NTH) FRu[i] = 0;
  for (int i = tid; i < 8*65; i += NTH) OST[i] = 0.f;
  __syncthreads();

  if (w == 0)
    wave_gru_fb<64,32,2>(wih0,whh0,bih0,bhh0,  0, XIN0, H0C, 0, 511, FRu, OST, X,M,L, out, b0, w, lane);
  else if (w == 1)
    wave_gru_fb<64,32,2>(wih0,whh0,bih0,bhh0, 16, XIN0, H0C, 0, 511, FRu, OST, X,M,L, out, b0, w, lane);
  else if (w == 2)
    wave_gru_fb<32,16,1>(wih1,whh1,bih1,bhh1,  0, H0C,  H1C, 1, 512, FRu, OST, X,M,L, out, b0, w, lane);
  else if (w == 4)
    wave_gru_fb<16, 8,1>(wih2,whh2,bih2,bhh2,  0, H1C,  H2C, 2, 513, FRu, OST, X,M,L, out, b0, w, lane);
  else if (w == 5)
    wave_gru_fb< 8,16,1>(wih3,whh3,bih3,bhh3,  0, H2C,  H3C, 3, 514, FRu, OST, X,M,L, out, b0, w, lane);
  else if (w == 3)
    wave_gru_fb<16,32,1>(wih4,whh4,bih4,bhh4,  0, H3C,  H4C, 4, 515, FRu, OST, X,M,L, out, b0, w, lane);
  else if (w == 6)
    wave_gru_fb<16,32,1>(wih4,whh4,bih4,bhh4, 16, H3C,  H4C, 4, 515, FRu, OST, X,M,L, out, b0, w, lane);
  else
    wave_out_fb(out_w, out_b, FRu, OST, X,M,L, out, b0, w, lane);
}

extern "C" void kernel_launch(void* const* d_in, const int* in_sizes, int n_in,
                              void* d_out, int out_size, void* d_ws, size_t ws_size,
                              hipStream_t stream)
{
  const float* X  = (const float*)d_in[0];
  const float* M  = (const float*)d_in[1];
  const float* L  = (const float*)d_in[2];
  const float* wp[20];
  for (int i = 0; i < 20; ++i) wp[i] = (const float*)d_in[3 + i];
  const float* ow = (const float*)d_in[23];
  const float* ob = (const float*)d_in[24];
  float* out = (float*)d_out;

  const size_t gi_bytes = (size_t)2048 * NT * 96 * sizeof(float);  // 402,653,184
  if (ws_size >= gi_bytes) {
    float* gi = (float*)d_ws;
    gi0_gemm<<<dim3(2048*4), dim3(256), 0, stream>>>(X, M, L, wp[0], wp[2], wp[3], gi);
    gru_rec<<<dim3(256), dim3(NTH), 0, stream>>>(
        gi, wp[1], wp[3],
        wp[4], wp[5], wp[6], wp[7],
        wp[8], wp[9], wp[10], wp[11],
        wp[12], wp[13], wp[14], wp[15],
        wp[16], wp[17], wp[18], wp[19],
        ow, ob, out);
  } else {
    gru_mfma<<<dim3(256), dim3(NTH), 0, stream>>>(
        X, M, L,
        wp[0], wp[1], wp[2], wp[3],
        wp[4], wp[5], wp[6], wp[7],
        wp[8], wp[9], wp[10], wp[11],
        wp[12], wp[13], wp[14], wp[15],
        wp[16], wp[17], wp[18], wp[19],
        ow, ob, out);
  }
}